// Round 6
// baseline (561.482 us; speedup 1.0000x reference)
//
#include <hip/hip_runtime.h>
#include <hip/hip_bf16.h>

// SPRGraphNet: embed -> 2x SAGEConv(mean) -> mean-pool per graph -> linear(64->10)
// Inputs detected fp32 (round 2). CSR + gather aggregation (rounds 3-5).
// Round 6: (a) privatized count (K=8 replicas) to break 16-deep same-address
// returning-atomic chains (round 5: 23.5 G/s vs 75 G/s non-returning);
// (b) gather fused into the 4x4 register-tiled layer GEMM (CSR is node-ordered
// so each block's edges are contiguous), eliminating the agg array.

#define KREP 8

struct WParams {
    const void* p[10];
    int off[11];
};

__device__ __forceinline__ float loadf(const void* p, int i, int f32) {
    return f32 ? ((const float*)p)[i]
               : __bfloat162float(((const __hip_bfloat16*)p)[i]);
}

static __global__ void detect_kernel(const void* probe, int n_bf16, int* flag) {
    __shared__ int bad;
    if (threadIdx.x == 0) bad = 0;
    __syncthreads();
    const __hip_bfloat16* p = (const __hip_bfloat16*)probe;
    int lbad = 0;
    for (int i = threadIdx.x; i < n_bf16; i += blockDim.x) {
        float v = __bfloat162float(p[i]);
        if (!(fabsf(v) <= 100.0f)) lbad = 1;   // catches huge AND NaN
    }
    if (lbad) atomicOr(&bad, 1);
    __syncthreads();
    if (threadIdx.x == 0) *flag = bad;         // 1 => inputs are fp32
}

static __global__ void convert_kernel(WParams wp, const int* __restrict__ flag,
                                      float* __restrict__ dst, int total) {
    int gid = blockIdx.x * blockDim.x + threadIdx.x;
    if (gid >= total) return;
    int f32 = *flag;
    int s = 0;
    while (gid >= wp.off[s + 1]) ++s;
    dst[gid] = loadf(wp.p[s], gid - wp.off[s], f32);
}

static __global__ void embed_kernel(const int* __restrict__ x,
                                    const float* __restrict__ semb,
                                    const float* __restrict__ cemb,
                                    float* __restrict__ h, int n_nodes) {
    int gid = blockIdx.x * blockDim.x + threadIdx.x;
    int node = gid >> 6, col = gid & 63;
    if (node >= n_nodes) return;
    float v;
    if (col < 32) {
        int s = x[node * 2];
        v = semb[s * 32 + col];
    } else {
        int c = x[node * 2 + 1];
        v = cemb[c * 32 + (col - 32)];
    }
    h[node * 64 + col] = v;
}

// Privatized count: replica k = blockIdx & 7. rank[e] = local arrival order.
static __global__ void count_rank_kernel(const int* __restrict__ tgt,
                                         int* __restrict__ cnt_rep,
                                         int* __restrict__ rank,
                                         int n_edges, int n_nodes) {
    int e = blockIdx.x * blockDim.x + threadIdx.x;
    if (e >= n_edges) return;
    int k = blockIdx.x & (KREP - 1);
    rank[e] = atomicAdd(&cnt_rep[(size_t)k * n_nodes + tgt[e]], 1);
}

// Per node: turn replica counts into exclusive bases (in place), total -> cnt.
static __global__ __launch_bounds__(256) void bases_kernel(
        int* __restrict__ cnt_rep, int* __restrict__ cnt, int n_nodes) {
    int n = blockIdx.x * blockDim.x + threadIdx.x;
    if (n >= n_nodes) return;
    int running = 0;
#pragma unroll
    for (int k = 0; k < KREP; ++k) {
        int* p = &cnt_rep[(size_t)k * n_nodes + n];
        int b = *p;
        *p = running;
        running += b;
    }
    cnt[n] = running;
}

// ---- prefix-sum (exclusive) over cnt -> rowptr[0..n], 3 kernels ----
static __global__ __launch_bounds__(256) void scan1_kernel(
        const int* __restrict__ cnt, int* __restrict__ tmp,
        int* __restrict__ bsum, int n) {
    __shared__ int s[256];
    int t = threadIdx.x;
    int i = blockIdx.x * 256 + t;
    s[t] = (i < n) ? cnt[i] : 0;
    __syncthreads();
#pragma unroll
    for (int d = 1; d < 256; d <<= 1) {
        int x = (t >= d) ? s[t - d] : 0;
        __syncthreads();
        s[t] += x;
        __syncthreads();
    }
    if (i < n) tmp[i] = s[t];                 // inclusive scan within block
    if (t == 255) bsum[blockIdx.x] = s[255];
}

static __global__ __launch_bounds__(1024) void scan2_kernel(
        int* __restrict__ bsum, int nb) {     // in-place inclusive scan, nb <= 1024
    __shared__ int s[1024];
    int t = threadIdx.x;
    s[t] = (t < nb) ? bsum[t] : 0;
    __syncthreads();
#pragma unroll
    for (int d = 1; d < 1024; d <<= 1) {
        int x = (t >= d) ? s[t - d] : 0;
        __syncthreads();
        s[t] += x;
        __syncthreads();
    }
    if (t < nb) bsum[t] = s[t];
}

static __global__ __launch_bounds__(256) void scan3_kernel(
        const int* __restrict__ tmp, const int* __restrict__ bsum,
        int* __restrict__ rowptr, int n) {
    int i = blockIdx.x * 256 + threadIdx.x;
    if (i >= n) return;
    int base = (blockIdx.x > 0) ? bsum[blockIdx.x - 1] : 0;
    rowptr[i + 1] = tmp[i] + base;            // exclusive: rowptr[k] = sum cnt[0..k-1]
    if (i == 0) rowptr[0] = 0;
}

// Fold rowptr into replica bases so fill needs one random read per edge.
static __global__ __launch_bounds__(256) void rebase_kernel(
        int* __restrict__ cnt_rep, const int* __restrict__ rowptr, int n_nodes) {
    int idx = blockIdx.x * blockDim.x + threadIdx.x;
    int total = KREP * n_nodes;
    if (idx >= total) return;
    int n = idx % n_nodes;
    cnt_rep[idx] += rowptr[n];
}

// Atomic-free CSR fill: slot = replica-base (incl. rowptr) + local rank.
static __global__ void fill_kernel(const int* __restrict__ src,
                                   const int* __restrict__ tgt,
                                   const int* __restrict__ cnt_rep,
                                   const int* __restrict__ rank,
                                   int* __restrict__ csr_src,
                                   int n_edges, int n_nodes) {
    int e = blockIdx.x * blockDim.x + threadIdx.x;
    if (e >= n_edges) return;
    int k = blockIdx.x & (KREP - 1);
    int t = tgt[e];
    csr_src[cnt_rep[(size_t)k * n_nodes + t] + rank[e]] = src[e];
}

// Fused gather + h_out = relu([mean(h_in[src]) | h_in] @ [wl; wr] + b).
// Block: 256 threads; tile = 64 nodes x 64 cols; 4x4 register tiling.
// Gather phase: 4 waves x 16 nodes; lane = 16*g + j, group g takes edges
// i % 4 == g, lane loads float4 of cols [4j,4j+4); shfl_xor cross-group reduce.
static __global__ __launch_bounds__(256) void fused_layer_kernel(
        const float* __restrict__ h_in, float* __restrict__ h_out,
        const int* __restrict__ rowptr, const int* __restrict__ csr_src,
        const float* __restrict__ wl, const float* __restrict__ wr,
        const float* __restrict__ b, int n_nodes) {
    __shared__ float inS[64][132];   // [node][k]: 0..63 = agg, 64..127 = self h
    __shared__ float wS[128][64];    // [k][col]: 0..63 = wl, 64..127 = wr
    int t = threadIdx.x;
    int base = blockIdx.x * 64;

    // stage weights
    const float4* wl4 = (const float4*)wl;
    const float4* wr4 = (const float4*)wr;
#pragma unroll
    for (int r = 0; r < 4; ++r) {
        int i = t + 256 * r;
        int k = i >> 4, c = (i & 15) * 4;
        *(float4*)&wS[k][c] = wl4[i];
        *(float4*)&wS[64 + k][c] = wr4[i];
    }

    // gather phase
    int wave = t >> 6, lane = t & 63;
    int g = lane >> 4, j = lane & 15;
    for (int it = 0; it < 16; ++it) {
        int n = wave * 16 + it;
        int node = base + n;
        int beg = 0, end = 0;
        if (node < n_nodes) { beg = rowptr[node]; end = rowptr[node + 1]; }
        float4 vh = make_float4(0.f, 0.f, 0.f, 0.f);
        if (g == 1 && node < n_nodes)
            vh = *(const float4*)&h_in[(size_t)node * 64 + j * 4];

        float4 acc = make_float4(0.f, 0.f, 0.f, 0.f);
        int i = beg + g;
        for (; i + 12 < end; i += 16) {
            int s0 = csr_src[i];
            int s1 = csr_src[i + 4];
            int s2 = csr_src[i + 8];
            int s3 = csr_src[i + 12];
            float4 v0 = *reinterpret_cast<const float4*>(h_in + (size_t)s0 * 64 + j * 4);
            float4 v1 = *reinterpret_cast<const float4*>(h_in + (size_t)s1 * 64 + j * 4);
            float4 v2 = *reinterpret_cast<const float4*>(h_in + (size_t)s2 * 64 + j * 4);
            float4 v3 = *reinterpret_cast<const float4*>(h_in + (size_t)s3 * 64 + j * 4);
            acc.x += v0.x + v1.x + v2.x + v3.x;
            acc.y += v0.y + v1.y + v2.y + v3.y;
            acc.z += v0.z + v1.z + v2.z + v3.z;
            acc.w += v0.w + v1.w + v2.w + v3.w;
        }
        for (; i < end; i += 4) {
            int s = csr_src[i];
            float4 v = *reinterpret_cast<const float4*>(h_in + (size_t)s * 64 + j * 4);
            acc.x += v.x; acc.y += v.y; acc.z += v.z; acc.w += v.w;
        }
#pragma unroll
        for (int m = 16; m < 64; m <<= 1) {
            acc.x += __shfl_xor(acc.x, m, 64);
            acc.y += __shfl_xor(acc.y, m, 64);
            acc.z += __shfl_xor(acc.z, m, 64);
            acc.w += __shfl_xor(acc.w, m, 64);
        }
        if (g == 0) {
            float inv = 1.0f / fmaxf((float)(end - beg), 1.0f);
            acc.x *= inv; acc.y *= inv; acc.z *= inv; acc.w *= inv;
            *(float4*)&inS[n][j * 4] = acc;
        } else if (g == 1) {
            *(float4*)&inS[n][64 + j * 4] = vh;
        }
    }
    __syncthreads();

    // GEMM phase
    int tx = t & 15, ty = t >> 4;
    int c0 = tx * 4, n0 = ty * 4;
    float4 bias = *(const float4*)&b[c0];
    float acc[4][4];
#pragma unroll
    for (int i = 0; i < 4; ++i) {
        acc[i][0] = bias.x; acc[i][1] = bias.y;
        acc[i][2] = bias.z; acc[i][3] = bias.w;
    }

#pragma unroll 4
    for (int k = 0; k < 128; k += 4) {
        float4 a0 = *(const float4*)&inS[n0 + 0][k];
        float4 a1 = *(const float4*)&inS[n0 + 1][k];
        float4 a2 = *(const float4*)&inS[n0 + 2][k];
        float4 a3 = *(const float4*)&inS[n0 + 3][k];
        float4 w0 = *(const float4*)&wS[k + 0][c0];
        float4 w1 = *(const float4*)&wS[k + 1][c0];
        float4 w2 = *(const float4*)&wS[k + 2][c0];
        float4 w3 = *(const float4*)&wS[k + 3][c0];
#define ROW(i, ai)                                                        \
        acc[i][0] = fmaf(ai.x, w0.x, fmaf(ai.y, w1.x, fmaf(ai.z, w2.x,    \
                    fmaf(ai.w, w3.x, acc[i][0]))));                       \
        acc[i][1] = fmaf(ai.x, w0.y, fmaf(ai.y, w1.y, fmaf(ai.z, w2.y,    \
                    fmaf(ai.w, w3.y, acc[i][1]))));                       \
        acc[i][2] = fmaf(ai.x, w0.z, fmaf(ai.y, w1.z, fmaf(ai.z, w2.z,    \
                    fmaf(ai.w, w3.z, acc[i][2]))));                       \
        acc[i][3] = fmaf(ai.x, w0.w, fmaf(ai.y, w1.w, fmaf(ai.z, w2.w,    \
                    fmaf(ai.w, w3.w, acc[i][3]))));
        ROW(0, a0) ROW(1, a1) ROW(2, a2) ROW(3, a3)
#undef ROW
    }

#pragma unroll
    for (int i = 0; i < 4; ++i) {
        int node = base + n0 + i;
        if (node < n_nodes) {
            float4 o;
            o.x = fmaxf(acc[i][0], 0.f);
            o.y = fmaxf(acc[i][1], 0.f);
            o.z = fmaxf(acc[i][2], 0.f);
            o.w = fmaxf(acc[i][3], 0.f);
            *(float4*)&h_out[(size_t)node * 64 + c0] = o;
        }
    }
}

// batch is sorted: binary-search [start,end) per graph; mean-pool then classify.
static __global__ __launch_bounds__(256) void pool_classify_kernel(
        const float* __restrict__ h, const int* __restrict__ batch,
        const float* __restrict__ wc, const float* __restrict__ bc,
        void* __restrict__ out, const int* __restrict__ flag, int n_nodes) {
    int g = blockIdx.x;
    int t = threadIdx.x;
    int lo = 0, hi = n_nodes;
    while (lo < hi) { int mid = (lo + hi) >> 1; if (batch[mid] < g) lo = mid + 1; else hi = mid; }
    int start = lo;
    hi = n_nodes;
    while (lo < hi) { int mid = (lo + hi) >> 1; if (batch[mid] < g + 1) lo = mid + 1; else hi = mid; }
    int end = lo;

    int r = t >> 6, o = t & 63;
    float partial = 0.0f;
    for (int n = start + r; n < end; n += 4) partial += h[(size_t)n * 64 + o];
    __shared__ float sred[4][64];
    __shared__ float pooled[64];
    sred[r][o] = partial;
    __syncthreads();
    if (r == 0) {
        float cntf = fmaxf((float)(end - start), 1.0f);
        pooled[o] = (sred[0][o] + sred[1][o] + sred[2][o] + sred[3][o]) / cntf;
    }
    __syncthreads();
    if (t < 10) {
        float acc = bc[t];
#pragma unroll
        for (int k = 0; k < 64; ++k)
            acc = fmaf(pooled[k], wc[k * 10 + t], acc);
        if (*flag) ((float*)out)[g * 10 + t] = acc;
        else       ((__hip_bfloat16*)out)[g * 10 + t] = __float2bfloat16(acc);
    }
}

extern "C" void kernel_launch(void* const* d_in, const int* in_sizes, int n_in,
                              void* d_out, int out_size, void* d_ws, size_t ws_size,
                              hipStream_t stream) {
    const int* x          = (const int*)d_in[0];
    const int* edge_index = (const int*)d_in[1];
    const int* batch      = (const int*)d_in[2];

    const int N = in_sizes[2];        // N_NODES
    const int E = in_sizes[1] / 2;    // edge_index is (2, E)
    const int G = out_size / 10;      // num_graphs
    const int NB = (N + 255) / 256;   // scan blocks (<=1024 required)

    // workspace layout (fp32 / int32)
    float* h       = (float*)d_ws;
    float* h2      = h + (size_t)N * 64;
    int*   cnt_rep = (int*)(h2 + (size_t)N * 64);   // KREP*N (memset to 0)
    int*   cnt     = cnt_rep + (size_t)KREP * N;    // N
    int*   rowptr  = cnt + N;                       // N+1
    int*   tmp     = rowptr + (N + 1);              // N
    int*   bsum    = tmp + N;                       // NB
    int*   rank    = bsum + NB;                     // E
    int*   csr_src = rank + E;                      // E
    float* wbuf    = (float*)(csr_src + E);

    WParams wp;
    int off = 0;
    for (int i = 0; i < 10; ++i) {
        wp.p[i] = d_in[4 + i];
        wp.off[i] = off;
        off += in_sizes[4 + i];
    }
    wp.off[10] = off;
    const int wtotal = off;

    float* semb_f = wbuf + wp.off[0];
    float* cemb_f = wbuf + wp.off[1];
    float* w1l_f  = wbuf + wp.off[2];
    float* w1r_f  = wbuf + wp.off[3];
    float* b1_f   = wbuf + wp.off[4];
    float* w2l_f  = wbuf + wp.off[5];
    float* w2r_f  = wbuf + wp.off[6];
    float* b2_f   = wbuf + wp.off[7];
    float* wc_f   = wbuf + wp.off[8];
    float* bc_f   = wbuf + wp.off[9];
    int*   flag   = (int*)(wbuf + wtotal);

    const int* src = edge_index;
    const int* tgt = edge_index + E;

    detect_kernel<<<1, 256, 0, stream>>>(d_in[4], 1024, flag);
    convert_kernel<<<(wtotal + 255) / 256, 256, 0, stream>>>(wp, flag, wbuf, wtotal);

    // zero replica counters
    hipMemsetAsync(cnt_rep, 0, (size_t)KREP * N * sizeof(int), stream);

    embed_kernel<<<(N * 64 + 255) / 256, 256, 0, stream>>>(x, semb_f, cemb_f, h, N);
    count_rank_kernel<<<(E + 255) / 256, 256, 0, stream>>>(tgt, cnt_rep, rank, E, N);
    bases_kernel<<<NB, 256, 0, stream>>>(cnt_rep, cnt, N);

    // CSR build
    scan1_kernel<<<NB, 256, 0, stream>>>(cnt, tmp, bsum, N);
    scan2_kernel<<<1, 1024, 0, stream>>>(bsum, NB);
    scan3_kernel<<<NB, 256, 0, stream>>>(tmp, bsum, rowptr, N);
    rebase_kernel<<<(KREP * N + 255) / 256, 256, 0, stream>>>(cnt_rep, rowptr, N);
    fill_kernel<<<(E + 255) / 256, 256, 0, stream>>>(src, tgt, cnt_rep, rank, csr_src, E, N);

    // layer 1: h -> h2 ; layer 2: h2 -> h
    fused_layer_kernel<<<(N + 63) / 64, 256, 0, stream>>>(h, h2, rowptr, csr_src,
                                                          w1l_f, w1r_f, b1_f, N);
    fused_layer_kernel<<<(N + 63) / 64, 256, 0, stream>>>(h2, h, rowptr, csr_src,
                                                          w2l_f, w2r_f, b2_f, N);

    // pool + classify
    pool_classify_kernel<<<G, 256, 0, stream>>>(h, batch, wc_f, bc_f, d_out, flag, N);
}

// Round 7
// 404.488 us; speedup vs baseline: 1.3881x; 1.3881x over previous
//
#include <hip/hip_runtime.h>
#include <hip/hip_bf16.h>

// SPRGraphNet: embed -> 2x SAGEConv(mean) -> mean-pool per graph -> linear(64->10)
// Inputs detected fp32 (round 2). CSR + gather aggregation (rounds 3-5).
// Round 7: REVERT round-6 gather+GEMM fusion (65KB LDS killed occupancy ->
// 17.6%, latency-bound gather starved; 172us vs 85us split). Keep privatized
// count (KREP=8) + atomic-free fill. Gather gets an unroll-2 remainder stage.

#define KREP 8

struct WParams {
    const void* p[10];
    int off[11];
};

__device__ __forceinline__ float loadf(const void* p, int i, int f32) {
    return f32 ? ((const float*)p)[i]
               : __bfloat162float(((const __hip_bfloat16*)p)[i]);
}

static __global__ void detect_kernel(const void* probe, int n_bf16, int* flag) {
    __shared__ int bad;
    if (threadIdx.x == 0) bad = 0;
    __syncthreads();
    const __hip_bfloat16* p = (const __hip_bfloat16*)probe;
    int lbad = 0;
    for (int i = threadIdx.x; i < n_bf16; i += blockDim.x) {
        float v = __bfloat162float(p[i]);
        if (!(fabsf(v) <= 100.0f)) lbad = 1;   // catches huge AND NaN
    }
    if (lbad) atomicOr(&bad, 1);
    __syncthreads();
    if (threadIdx.x == 0) *flag = bad;         // 1 => inputs are fp32
}

static __global__ void convert_kernel(WParams wp, const int* __restrict__ flag,
                                      float* __restrict__ dst, int total) {
    int gid = blockIdx.x * blockDim.x + threadIdx.x;
    if (gid >= total) return;
    int f32 = *flag;
    int s = 0;
    while (gid >= wp.off[s + 1]) ++s;
    dst[gid] = loadf(wp.p[s], gid - wp.off[s], f32);
}

static __global__ void embed_kernel(const int* __restrict__ x,
                                    const float* __restrict__ semb,
                                    const float* __restrict__ cemb,
                                    float* __restrict__ h, int n_nodes) {
    int gid = blockIdx.x * blockDim.x + threadIdx.x;
    int node = gid >> 6, col = gid & 63;
    if (node >= n_nodes) return;
    float v;
    if (col < 32) {
        int s = x[node * 2];
        v = semb[s * 32 + col];
    } else {
        int c = x[node * 2 + 1];
        v = cemb[c * 32 + (col - 32)];
    }
    h[node * 64 + col] = v;
}

// Privatized count: replica k = blockIdx & 7. rank[e] = local arrival order.
static __global__ void count_rank_kernel(const int* __restrict__ tgt,
                                         int* __restrict__ cnt_rep,
                                         int* __restrict__ rank,
                                         int n_edges, int n_nodes) {
    int e = blockIdx.x * blockDim.x + threadIdx.x;
    if (e >= n_edges) return;
    int k = blockIdx.x & (KREP - 1);
    rank[e] = atomicAdd(&cnt_rep[(size_t)k * n_nodes + tgt[e]], 1);
}

// Per node: turn replica counts into exclusive bases (in place), total -> cnt.
static __global__ __launch_bounds__(256) void bases_kernel(
        int* __restrict__ cnt_rep, int* __restrict__ cnt, int n_nodes) {
    int n = blockIdx.x * blockDim.x + threadIdx.x;
    if (n >= n_nodes) return;
    int running = 0;
#pragma unroll
    for (int k = 0; k < KREP; ++k) {
        int* p = &cnt_rep[(size_t)k * n_nodes + n];
        int b = *p;
        *p = running;
        running += b;
    }
    cnt[n] = running;
}

// ---- prefix-sum (exclusive) over cnt -> rowptr[0..n], 3 kernels ----
static __global__ __launch_bounds__(256) void scan1_kernel(
        const int* __restrict__ cnt, int* __restrict__ tmp,
        int* __restrict__ bsum, int n) {
    __shared__ int s[256];
    int t = threadIdx.x;
    int i = blockIdx.x * 256 + t;
    s[t] = (i < n) ? cnt[i] : 0;
    __syncthreads();
#pragma unroll
    for (int d = 1; d < 256; d <<= 1) {
        int x = (t >= d) ? s[t - d] : 0;
        __syncthreads();
        s[t] += x;
        __syncthreads();
    }
    if (i < n) tmp[i] = s[t];                 // inclusive scan within block
    if (t == 255) bsum[blockIdx.x] = s[255];
}

static __global__ __launch_bounds__(1024) void scan2_kernel(
        int* __restrict__ bsum, int nb) {     // in-place inclusive scan, nb <= 1024
    __shared__ int s[1024];
    int t = threadIdx.x;
    s[t] = (t < nb) ? bsum[t] : 0;
    __syncthreads();
#pragma unroll
    for (int d = 1; d < 1024; d <<= 1) {
        int x = (t >= d) ? s[t - d] : 0;
        __syncthreads();
        s[t] += x;
        __syncthreads();
    }
    if (t < nb) bsum[t] = s[t];
}

static __global__ __launch_bounds__(256) void scan3_kernel(
        const int* __restrict__ tmp, const int* __restrict__ bsum,
        int* __restrict__ rowptr, int n) {
    int i = blockIdx.x * 256 + threadIdx.x;
    if (i >= n) return;
    int base = (blockIdx.x > 0) ? bsum[blockIdx.x - 1] : 0;
    rowptr[i + 1] = tmp[i] + base;            // exclusive: rowptr[k] = sum cnt[0..k-1]
    if (i == 0) rowptr[0] = 0;
}

// Fold rowptr into replica bases so fill needs one random read per edge.
static __global__ __launch_bounds__(256) void rebase_kernel(
        int* __restrict__ cnt_rep, const int* __restrict__ rowptr, int n_nodes) {
    int idx = blockIdx.x * blockDim.x + threadIdx.x;
    int total = KREP * n_nodes;
    if (idx >= total) return;
    int n = idx % n_nodes;
    cnt_rep[idx] += rowptr[n];
}

// Atomic-free CSR fill: slot = replica-base (incl. rowptr) + local rank.
static __global__ void fill_kernel(const int* __restrict__ src,
                                   const int* __restrict__ tgt,
                                   const int* __restrict__ cnt_rep,
                                   const int* __restrict__ rank,
                                   int* __restrict__ csr_src,
                                   int n_edges, int n_nodes) {
    int e = blockIdx.x * blockDim.x + threadIdx.x;
    if (e >= n_edges) return;
    int k = blockIdx.x & (KREP - 1);
    int t = tgt[e];
    csr_src[cnt_rep[(size_t)k * n_nodes + t] + rank[e]] = src[e];
}

// One wave per node. lane = 16*g + j: group g handles edges (i % 4 == g),
// lane loads float4 at cols [4j, 4j+4). Cross-group reduce via shfl_xor.
// Main loop: 4 edges in flight/lane; remainder: 2 in flight.
static __global__ __launch_bounds__(256) void gather_kernel(
        const float* __restrict__ h, const int* __restrict__ rowptr,
        const int* __restrict__ csr_src, float* __restrict__ agg, int n_nodes) {
    int node = (blockIdx.x * 256 + threadIdx.x) >> 6;
    int lane = threadIdx.x & 63;
    if (node >= n_nodes) return;
    int g = lane >> 4, j = lane & 15;
    int beg = rowptr[node], end = rowptr[node + 1];

    float4 acc = make_float4(0.f, 0.f, 0.f, 0.f);
    int i = beg + g;
    for (; i + 12 < end; i += 16) {
        int s0 = csr_src[i];
        int s1 = csr_src[i + 4];
        int s2 = csr_src[i + 8];
        int s3 = csr_src[i + 12];
        float4 v0 = *reinterpret_cast<const float4*>(h + (size_t)s0 * 64 + j * 4);
        float4 v1 = *reinterpret_cast<const float4*>(h + (size_t)s1 * 64 + j * 4);
        float4 v2 = *reinterpret_cast<const float4*>(h + (size_t)s2 * 64 + j * 4);
        float4 v3 = *reinterpret_cast<const float4*>(h + (size_t)s3 * 64 + j * 4);
        acc.x += v0.x + v1.x + v2.x + v3.x;
        acc.y += v0.y + v1.y + v2.y + v3.y;
        acc.z += v0.z + v1.z + v2.z + v3.z;
        acc.w += v0.w + v1.w + v2.w + v3.w;
    }
    for (; i + 4 < end; i += 8) {
        int s0 = csr_src[i];
        int s1 = csr_src[i + 4];
        float4 v0 = *reinterpret_cast<const float4*>(h + (size_t)s0 * 64 + j * 4);
        float4 v1 = *reinterpret_cast<const float4*>(h + (size_t)s1 * 64 + j * 4);
        acc.x += v0.x + v1.x;
        acc.y += v0.y + v1.y;
        acc.z += v0.z + v1.z;
        acc.w += v0.w + v1.w;
    }
    if (i < end) {
        int s = csr_src[i];
        float4 v = *reinterpret_cast<const float4*>(h + (size_t)s * 64 + j * 4);
        acc.x += v.x; acc.y += v.y; acc.z += v.z; acc.w += v.w;
    }
    // reduce across the 4 edge-groups (lanes j, j+16, j+32, j+48)
#pragma unroll
    for (int m = 16; m < 64; m <<= 1) {
        acc.x += __shfl_xor(acc.x, m, 64);
        acc.y += __shfl_xor(acc.y, m, 64);
        acc.z += __shfl_xor(acc.z, m, 64);
        acc.w += __shfl_xor(acc.w, m, 64);
    }
    if (g == 0) {
        float inv = 1.0f / fmaxf((float)(end - beg), 1.0f);
        acc.x *= inv; acc.y *= inv; acc.z *= inv; acc.w *= inv;
        *reinterpret_cast<float4*>(agg + (size_t)node * 64 + j * 4) = acc;
    }
}

// h = relu([agg | h] @ [wl; wr] + b), in place. 4x4 register tiling.
// Block: 256 threads = 16x16; tile = 64 nodes x 64 cols.
static __global__ __launch_bounds__(256) void layer_kernel(
        float* __restrict__ h, const float* __restrict__ agg,
        const float* __restrict__ wl, const float* __restrict__ wr,
        const float* __restrict__ b, int n_nodes) {
    __shared__ float inS[64][132];   // [node][k], +4 pad: 16B-aligned rows, 2-way banks
    __shared__ float wS[128][64];    // [k][col], rows 0..63 = wl, 64..127 = wr
    int t = threadIdx.x;
    int base = blockIdx.x * 64;

    const float4* wl4 = (const float4*)wl;
    const float4* wr4 = (const float4*)wr;
#pragma unroll
    for (int r = 0; r < 4; ++r) {
        int i = t + 256 * r;
        int k = i >> 4, c = (i & 15) * 4;
        *(float4*)&wS[k][c] = wl4[i];
        *(float4*)&wS[64 + k][c] = wr4[i];
    }
#pragma unroll
    for (int r = 0; r < 4; ++r) {
        int i = t + 256 * r;
        int n = i >> 4, c = (i & 15) * 4;
        int node = base + n;
        float4 va = make_float4(0.f, 0.f, 0.f, 0.f);
        float4 vh = make_float4(0.f, 0.f, 0.f, 0.f);
        if (node < n_nodes) {
            va = *(const float4*)&agg[(size_t)node * 64 + c];
            vh = *(const float4*)&h[(size_t)node * 64 + c];
        }
        *(float4*)&inS[n][c] = va;
        *(float4*)&inS[n][64 + c] = vh;
    }
    __syncthreads();

    int tx = t & 15, ty = t >> 4;
    int c0 = tx * 4, n0 = ty * 4;
    float4 bias = *(const float4*)&b[c0];
    float acc[4][4];
#pragma unroll
    for (int i = 0; i < 4; ++i) {
        acc[i][0] = bias.x; acc[i][1] = bias.y;
        acc[i][2] = bias.z; acc[i][3] = bias.w;
    }

#pragma unroll 4
    for (int k = 0; k < 128; k += 4) {
        float4 a0 = *(const float4*)&inS[n0 + 0][k];
        float4 a1 = *(const float4*)&inS[n0 + 1][k];
        float4 a2 = *(const float4*)&inS[n0 + 2][k];
        float4 a3 = *(const float4*)&inS[n0 + 3][k];
        float4 w0 = *(const float4*)&wS[k + 0][c0];
        float4 w1 = *(const float4*)&wS[k + 1][c0];
        float4 w2 = *(const float4*)&wS[k + 2][c0];
        float4 w3 = *(const float4*)&wS[k + 3][c0];
#define ROW(i, ai)                                                        \
        acc[i][0] = fmaf(ai.x, w0.x, fmaf(ai.y, w1.x, fmaf(ai.z, w2.x,    \
                    fmaf(ai.w, w3.x, acc[i][0]))));                       \
        acc[i][1] = fmaf(ai.x, w0.y, fmaf(ai.y, w1.y, fmaf(ai.z, w2.y,    \
                    fmaf(ai.w, w3.y, acc[i][1]))));                       \
        acc[i][2] = fmaf(ai.x, w0.z, fmaf(ai.y, w1.z, fmaf(ai.z, w2.z,    \
                    fmaf(ai.w, w3.z, acc[i][2]))));                       \
        acc[i][3] = fmaf(ai.x, w0.w, fmaf(ai.y, w1.w, fmaf(ai.z, w2.w,    \
                    fmaf(ai.w, w3.w, acc[i][3]))));
        ROW(0, a0) ROW(1, a1) ROW(2, a2) ROW(3, a3)
#undef ROW
    }

#pragma unroll
    for (int i = 0; i < 4; ++i) {
        int node = base + n0 + i;
        if (node < n_nodes) {
            float4 o;
            o.x = fmaxf(acc[i][0], 0.f);
            o.y = fmaxf(acc[i][1], 0.f);
            o.z = fmaxf(acc[i][2], 0.f);
            o.w = fmaxf(acc[i][3], 0.f);
            *(float4*)&h[(size_t)node * 64 + c0] = o;
        }
    }
}

// batch is sorted: binary-search [start,end) per graph; mean-pool then classify.
static __global__ __launch_bounds__(256) void pool_classify_kernel(
        const float* __restrict__ h, const int* __restrict__ batch,
        const float* __restrict__ wc, const float* __restrict__ bc,
        void* __restrict__ out, const int* __restrict__ flag, int n_nodes) {
    int g = blockIdx.x;
    int t = threadIdx.x;
    int lo = 0, hi = n_nodes;
    while (lo < hi) { int mid = (lo + hi) >> 1; if (batch[mid] < g) lo = mid + 1; else hi = mid; }
    int start = lo;
    hi = n_nodes;
    while (lo < hi) { int mid = (lo + hi) >> 1; if (batch[mid] < g + 1) lo = mid + 1; else hi = mid; }
    int end = lo;

    int r = t >> 6, o = t & 63;
    float partial = 0.0f;
    for (int n = start + r; n < end; n += 4) partial += h[(size_t)n * 64 + o];
    __shared__ float sred[4][64];
    __shared__ float pooled[64];
    sred[r][o] = partial;
    __syncthreads();
    if (r == 0) {
        float cntf = fmaxf((float)(end - start), 1.0f);
        pooled[o] = (sred[0][o] + sred[1][o] + sred[2][o] + sred[3][o]) / cntf;
    }
    __syncthreads();
    if (t < 10) {
        float acc = bc[t];
#pragma unroll
        for (int k = 0; k < 64; ++k)
            acc = fmaf(pooled[k], wc[k * 10 + t], acc);
        if (*flag) ((float*)out)[g * 10 + t] = acc;
        else       ((__hip_bfloat16*)out)[g * 10 + t] = __float2bfloat16(acc);
    }
}

extern "C" void kernel_launch(void* const* d_in, const int* in_sizes, int n_in,
                              void* d_out, int out_size, void* d_ws, size_t ws_size,
                              hipStream_t stream) {
    const int* x          = (const int*)d_in[0];
    const int* edge_index = (const int*)d_in[1];
    const int* batch      = (const int*)d_in[2];

    const int N = in_sizes[2];        // N_NODES
    const int E = in_sizes[1] / 2;    // edge_index is (2, E)
    const int G = out_size / 10;      // num_graphs
    const int NB = (N + 255) / 256;   // scan blocks (<=1024 required)

    // workspace layout (fp32 / int32)
    float* h       = (float*)d_ws;
    float* agg     = h + (size_t)N * 64;
    int*   cnt_rep = (int*)(agg + (size_t)N * 64);  // KREP*N (memset to 0)
    int*   cnt     = cnt_rep + (size_t)KREP * N;    // N
    int*   rowptr  = cnt + N;                       // N+1
    int*   tmp     = rowptr + (N + 1);              // N
    int*   bsum    = tmp + N;                       // NB
    int*   rank    = bsum + NB;                     // E
    int*   csr_src = rank + E;                      // E
    float* wbuf    = (float*)(csr_src + E);

    WParams wp;
    int off = 0;
    for (int i = 0; i < 10; ++i) {
        wp.p[i] = d_in[4 + i];
        wp.off[i] = off;
        off += in_sizes[4 + i];
    }
    wp.off[10] = off;
    const int wtotal = off;

    float* semb_f = wbuf + wp.off[0];
    float* cemb_f = wbuf + wp.off[1];
    float* w1l_f  = wbuf + wp.off[2];
    float* w1r_f  = wbuf + wp.off[3];
    float* b1_f   = wbuf + wp.off[4];
    float* w2l_f  = wbuf + wp.off[5];
    float* w2r_f  = wbuf + wp.off[6];
    float* b2_f   = wbuf + wp.off[7];
    float* wc_f   = wbuf + wp.off[8];
    float* bc_f   = wbuf + wp.off[9];
    int*   flag   = (int*)(wbuf + wtotal);

    const int* src = edge_index;
    const int* tgt = edge_index + E;

    detect_kernel<<<1, 256, 0, stream>>>(d_in[4], 1024, flag);
    convert_kernel<<<(wtotal + 255) / 256, 256, 0, stream>>>(wp, flag, wbuf, wtotal);

    // zero replica counters
    hipMemsetAsync(cnt_rep, 0, (size_t)KREP * N * sizeof(int), stream);

    embed_kernel<<<(N * 64 + 255) / 256, 256, 0, stream>>>(x, semb_f, cemb_f, h, N);
    count_rank_kernel<<<(E + 255) / 256, 256, 0, stream>>>(tgt, cnt_rep, rank, E, N);
    bases_kernel<<<NB, 256, 0, stream>>>(cnt_rep, cnt, N);

    // CSR build
    scan1_kernel<<<NB, 256, 0, stream>>>(cnt, tmp, bsum, N);
    scan2_kernel<<<1, 1024, 0, stream>>>(bsum, NB);
    scan3_kernel<<<NB, 256, 0, stream>>>(tmp, bsum, rowptr, N);
    rebase_kernel<<<(KREP * N + 255) / 256, 256, 0, stream>>>(cnt_rep, rowptr, N);
    fill_kernel<<<(E + 255) / 256, 256, 0, stream>>>(src, tgt, cnt_rep, rank, csr_src, E, N);

    // layer 1
    gather_kernel<<<(N * 64 + 255) / 256, 256, 0, stream>>>(h, rowptr, csr_src, agg, N);
    layer_kernel<<<(N + 63) / 64, 256, 0, stream>>>(h, agg, w1l_f, w1r_f, b1_f, N);

    // layer 2
    gather_kernel<<<(N * 64 + 255) / 256, 256, 0, stream>>>(h, rowptr, csr_src, agg, N);
    layer_kernel<<<(N + 63) / 64, 256, 0, stream>>>(h, agg, w2l_f, w2r_f, b2_f, N);

    // pool + classify
    pool_classify_kernel<<<G, 256, 0, stream>>>(h, batch, wc_f, bc_f, d_out, flag, N);
}

// Round 8
// 365.635 us; speedup vs baseline: 1.5356x; 1.1063x over previous
//
#include <hip/hip_runtime.h>
#include <hip/hip_bf16.h>

// SPRGraphNet: embed -> 2x SAGEConv(mean) -> mean-pool per graph -> linear(64->10)
// Inputs detected fp32 (round 2). CSR + gather aggregation (rounds 3-7).
// Round 8: (a) h stored as bf16 (halves gather cache-line transactions;
// accumulation stays fp32); (b) CSR-build chain merged: bases->scan1,
// rebase->scan3, detect inlined into convert/pool. KREP=8 kept (63us floor is
// per-CU returning-atomic issue cost ~24cyc, not chain depth — round 7).

#define KREP 8

struct WParams {
    const void* p[10];
    int off[11];
};

__device__ __forceinline__ float b2f(unsigned short u) {
    return __uint_as_float(((unsigned)u) << 16);
}
__device__ __forceinline__ unsigned short f2b(float f) {
    unsigned x = __float_as_uint(f);
    return (unsigned short)((x + 0x7fff + ((x >> 16) & 1)) >> 16);   // RNE
}
__device__ __forceinline__ float4 b4_to_f4(ushort4 u) {
    return make_float4(b2f(u.x), b2f(u.y), b2f(u.z), b2f(u.w));
}

// Shared inline dtype detection: read first n bf16 of probe; fp32 data
// reinterpreted as bf16 shows |v|>100 or NaN among elements.
__device__ __forceinline__ int detect_f32(const void* probe, int n_bf16) {
    __shared__ int bad;
    if (threadIdx.x == 0) bad = 0;
    __syncthreads();
    const __hip_bfloat16* p = (const __hip_bfloat16*)probe;
    int lbad = 0;
    for (int i = threadIdx.x; i < n_bf16; i += blockDim.x) {
        float v = __bfloat162float(p[i]);
        if (!(fabsf(v) <= 100.0f)) lbad = 1;
    }
    if (lbad) atomicOr(&bad, 1);
    __syncthreads();
    return bad;
}

__device__ __forceinline__ float loadf(const void* p, int i, int f32) {
    return f32 ? ((const float*)p)[i]
               : __bfloat162float(((const __hip_bfloat16*)p)[i]);
}

static __global__ void convert_kernel(WParams wp, const void* probe,
                                      float* __restrict__ dst, int total) {
    int f32 = detect_f32(probe, 1024);
    int gid = blockIdx.x * blockDim.x + threadIdx.x;
    if (gid >= total) return;
    int s = 0;
    while (gid >= wp.off[s + 1]) ++s;
    dst[gid] = loadf(wp.p[s], gid - wp.off[s], f32);
}

static __global__ void embed_kernel(const int* __restrict__ x,
                                    const float* __restrict__ semb,
                                    const float* __restrict__ cemb,
                                    unsigned short* __restrict__ h, int n_nodes) {
    int gid = blockIdx.x * blockDim.x + threadIdx.x;
    int node = gid >> 6, col = gid & 63;
    if (node >= n_nodes) return;
    float v;
    if (col < 32) {
        int s = x[node * 2];
        v = semb[s * 32 + col];
    } else {
        int c = x[node * 2 + 1];
        v = cemb[c * 32 + (col - 32)];
    }
    h[node * 64 + col] = f2b(v);
}

// Privatized count: replica k = blockIdx & 7. rank[e] = local arrival order.
static __global__ void count_rank_kernel(const int* __restrict__ tgt,
                                         int* __restrict__ cnt_rep,
                                         int* __restrict__ rank,
                                         int n_edges, int n_nodes) {
    int e = blockIdx.x * blockDim.x + threadIdx.x;
    if (e >= n_edges) return;
    int k = blockIdx.x & (KREP - 1);
    rank[e] = atomicAdd(&cnt_rep[(size_t)k * n_nodes + tgt[e]], 1);
}

// scan1: node totals from the 8 replicas + block-inclusive scan.
static __global__ __launch_bounds__(256) void scan1_kernel(
        const int* __restrict__ cnt_rep, int* __restrict__ tmp,
        int* __restrict__ bsum, int n) {
    __shared__ int s[256];
    int t = threadIdx.x;
    int i = blockIdx.x * 256 + t;
    int total = 0;
    if (i < n) {
#pragma unroll
        for (int k = 0; k < KREP; ++k) total += cnt_rep[(size_t)k * n + i];
    }
    s[t] = total;
    __syncthreads();
#pragma unroll
    for (int d = 1; d < 256; d <<= 1) {
        int x = (t >= d) ? s[t - d] : 0;
        __syncthreads();
        s[t] += x;
        __syncthreads();
    }
    if (i < n) tmp[i] = s[t];
    if (t == 255) bsum[blockIdx.x] = s[255];
}

static __global__ __launch_bounds__(1024) void scan2_kernel(
        int* __restrict__ bsum, int nb) {     // in-place inclusive scan, nb <= 1024
    __shared__ int s[1024];
    int t = threadIdx.x;
    s[t] = (t < nb) ? bsum[t] : 0;
    __syncthreads();
#pragma unroll
    for (int d = 1; d < 1024; d <<= 1) {
        int x = (t >= d) ? s[t - d] : 0;
        __syncthreads();
        s[t] += x;
        __syncthreads();
    }
    if (t < nb) bsum[t] = s[t];
}

// scan3: write rowptr AND final replica bases (exclusive, rowptr folded in).
static __global__ __launch_bounds__(256) void scan3_kernel(
        const int* __restrict__ tmp, const int* __restrict__ bsum,
        int* __restrict__ rowptr, int* __restrict__ cnt_rep, int n) {
    int i = blockIdx.x * 256 + threadIdx.x;
    if (i >= n) return;
    int bbase = (blockIdx.x > 0) ? bsum[blockIdx.x - 1] : 0;
    int incl = tmp[i] + bbase;                // rowptr[i+1]
    rowptr[i + 1] = incl;
    if (i == 0) rowptr[0] = 0;
    // exclusive start for node i = incl - total_i; fold into replica bases
    int total = 0;
    int c[KREP];
#pragma unroll
    for (int k = 0; k < KREP; ++k) { c[k] = cnt_rep[(size_t)k * n + i]; total += c[k]; }
    int running = incl - total;
#pragma unroll
    for (int k = 0; k < KREP; ++k) {
        cnt_rep[(size_t)k * n + i] = running;
        running += c[k];
    }
}

// Atomic-free CSR fill: slot = replica-base (incl. rowptr) + local rank.
static __global__ void fill_kernel(const int* __restrict__ src,
                                   const int* __restrict__ tgt,
                                   const int* __restrict__ cnt_rep,
                                   const int* __restrict__ rank,
                                   int* __restrict__ csr_src,
                                   int n_edges, int n_nodes) {
    int e = blockIdx.x * blockDim.x + threadIdx.x;
    if (e >= n_edges) return;
    int k = blockIdx.x & (KREP - 1);
    int t = tgt[e];
    csr_src[cnt_rep[(size_t)k * n_nodes + t] + rank[e]] = src[e];
}

// One wave per node. lane = 16*g + j: group g handles edges (i % 4 == g),
// lane loads ushort4 (4 bf16 cols). Cross-group reduce via shfl_xor.
static __global__ __launch_bounds__(256) void gather_kernel(
        const unsigned short* __restrict__ h, const int* __restrict__ rowptr,
        const int* __restrict__ csr_src, float* __restrict__ agg, int n_nodes) {
    int node = (blockIdx.x * 256 + threadIdx.x) >> 6;
    int lane = threadIdx.x & 63;
    if (node >= n_nodes) return;
    int g = lane >> 4, j = lane & 15;
    int beg = rowptr[node], end = rowptr[node + 1];

    float4 acc = make_float4(0.f, 0.f, 0.f, 0.f);
    int i = beg + g;
    for (; i + 12 < end; i += 16) {
        int s0 = csr_src[i];
        int s1 = csr_src[i + 4];
        int s2 = csr_src[i + 8];
        int s3 = csr_src[i + 12];
        float4 v0 = b4_to_f4(*reinterpret_cast<const ushort4*>(h + (size_t)s0 * 64 + j * 4));
        float4 v1 = b4_to_f4(*reinterpret_cast<const ushort4*>(h + (size_t)s1 * 64 + j * 4));
        float4 v2 = b4_to_f4(*reinterpret_cast<const ushort4*>(h + (size_t)s2 * 64 + j * 4));
        float4 v3 = b4_to_f4(*reinterpret_cast<const ushort4*>(h + (size_t)s3 * 64 + j * 4));
        acc.x += v0.x + v1.x + v2.x + v3.x;
        acc.y += v0.y + v1.y + v2.y + v3.y;
        acc.z += v0.z + v1.z + v2.z + v3.z;
        acc.w += v0.w + v1.w + v2.w + v3.w;
    }
    for (; i + 4 < end; i += 8) {
        int s0 = csr_src[i];
        int s1 = csr_src[i + 4];
        float4 v0 = b4_to_f4(*reinterpret_cast<const ushort4*>(h + (size_t)s0 * 64 + j * 4));
        float4 v1 = b4_to_f4(*reinterpret_cast<const ushort4*>(h + (size_t)s1 * 64 + j * 4));
        acc.x += v0.x + v1.x;
        acc.y += v0.y + v1.y;
        acc.z += v0.z + v1.z;
        acc.w += v0.w + v1.w;
    }
    if (i < end) {
        int s = csr_src[i];
        float4 v = b4_to_f4(*reinterpret_cast<const ushort4*>(h + (size_t)s * 64 + j * 4));
        acc.x += v.x; acc.y += v.y; acc.z += v.z; acc.w += v.w;
    }
#pragma unroll
    for (int m = 16; m < 64; m <<= 1) {
        acc.x += __shfl_xor(acc.x, m, 64);
        acc.y += __shfl_xor(acc.y, m, 64);
        acc.z += __shfl_xor(acc.z, m, 64);
        acc.w += __shfl_xor(acc.w, m, 64);
    }
    if (g == 0) {
        float inv = 1.0f / fmaxf((float)(end - beg), 1.0f);
        acc.x *= inv; acc.y *= inv; acc.z *= inv; acc.w *= inv;
        *reinterpret_cast<float4*>(agg + (size_t)node * 64 + j * 4) = acc;
    }
}

// h = relu([agg | h] @ [wl; wr] + b), in place (bf16 h, fp32 agg/compute).
// Block: 256 threads = 16x16; tile = 64 nodes x 64 cols; 4x4 register tiling.
static __global__ __launch_bounds__(256) void layer_kernel(
        unsigned short* __restrict__ h, const float* __restrict__ agg,
        const float* __restrict__ wl, const float* __restrict__ wr,
        const float* __restrict__ b, int n_nodes) {
    __shared__ float inS[64][132];   // [node][k], +4 pad
    __shared__ float wS[128][64];    // [k][col], rows 0..63 = wl, 64..127 = wr
    int t = threadIdx.x;
    int base = blockIdx.x * 64;

    const float4* wl4 = (const float4*)wl;
    const float4* wr4 = (const float4*)wr;
#pragma unroll
    for (int r = 0; r < 4; ++r) {
        int i = t + 256 * r;
        int k = i >> 4, c = (i & 15) * 4;
        *(float4*)&wS[k][c] = wl4[i];
        *(float4*)&wS[64 + k][c] = wr4[i];
    }
#pragma unroll
    for (int r = 0; r < 4; ++r) {
        int i = t + 256 * r;
        int n = i >> 4, c = (i & 15) * 4;
        int node = base + n;
        float4 va = make_float4(0.f, 0.f, 0.f, 0.f);
        float4 vh = make_float4(0.f, 0.f, 0.f, 0.f);
        if (node < n_nodes) {
            va = *(const float4*)&agg[(size_t)node * 64 + c];
            vh = b4_to_f4(*(const ushort4*)&h[(size_t)node * 64 + c]);
        }
        *(float4*)&inS[n][c] = va;
        *(float4*)&inS[n][64 + c] = vh;
    }
    __syncthreads();

    int tx = t & 15, ty = t >> 4;
    int c0 = tx * 4, n0 = ty * 4;
    float4 bias = *(const float4*)&b[c0];
    float acc[4][4];
#pragma unroll
    for (int i = 0; i < 4; ++i) {
        acc[i][0] = bias.x; acc[i][1] = bias.y;
        acc[i][2] = bias.z; acc[i][3] = bias.w;
    }

#pragma unroll 4
    for (int k = 0; k < 128; k += 4) {
        float4 a0 = *(const float4*)&inS[n0 + 0][k];
        float4 a1 = *(const float4*)&inS[n0 + 1][k];
        float4 a2 = *(const float4*)&inS[n0 + 2][k];
        float4 a3 = *(const float4*)&inS[n0 + 3][k];
        float4 w0 = *(const float4*)&wS[k + 0][c0];
        float4 w1 = *(const float4*)&wS[k + 1][c0];
        float4 w2 = *(const float4*)&wS[k + 2][c0];
        float4 w3 = *(const float4*)&wS[k + 3][c0];
#define ROW(i, ai)                                                        \
        acc[i][0] = fmaf(ai.x, w0.x, fmaf(ai.y, w1.x, fmaf(ai.z, w2.x,    \
                    fmaf(ai.w, w3.x, acc[i][0]))));                       \
        acc[i][1] = fmaf(ai.x, w0.y, fmaf(ai.y, w1.y, fmaf(ai.z, w2.y,    \
                    fmaf(ai.w, w3.y, acc[i][1]))));                       \
        acc[i][2] = fmaf(ai.x, w0.z, fmaf(ai.y, w1.z, fmaf(ai.z, w2.z,    \
                    fmaf(ai.w, w3.z, acc[i][2]))));                       \
        acc[i][3] = fmaf(ai.x, w0.w, fmaf(ai.y, w1.w, fmaf(ai.z, w2.w,    \
                    fmaf(ai.w, w3.w, acc[i][3]))));
        ROW(0, a0) ROW(1, a1) ROW(2, a2) ROW(3, a3)
#undef ROW
    }

#pragma unroll
    for (int i = 0; i < 4; ++i) {
        int node = base + n0 + i;
        if (node < n_nodes) {
            ushort4 o;
            o.x = f2b(fmaxf(acc[i][0], 0.f));
            o.y = f2b(fmaxf(acc[i][1], 0.f));
            o.z = f2b(fmaxf(acc[i][2], 0.f));
            o.w = f2b(fmaxf(acc[i][3], 0.f));
            *(ushort4*)&h[(size_t)node * 64 + c0] = o;
        }
    }
}

// batch is sorted: binary-search [start,end) per graph; mean-pool then classify.
static __global__ __launch_bounds__(256) void pool_classify_kernel(
        const unsigned short* __restrict__ h, const int* __restrict__ batch,
        const float* __restrict__ wc, const float* __restrict__ bc,
        void* __restrict__ out, const void* probe, int n_nodes) {
    int f32 = detect_f32(probe, 1024);
    int g = blockIdx.x;
    int t = threadIdx.x;
    int lo = 0, hi = n_nodes;
    while (lo < hi) { int mid = (lo + hi) >> 1; if (batch[mid] < g) lo = mid + 1; else hi = mid; }
    int start = lo;
    hi = n_nodes;
    while (lo < hi) { int mid = (lo + hi) >> 1; if (batch[mid] < g + 1) lo = mid + 1; else hi = mid; }
    int end = lo;

    int r = t >> 6, o = t & 63;
    float partial = 0.0f;
    for (int n = start + r; n < end; n += 4) partial += b2f(h[(size_t)n * 64 + o]);
    __shared__ float sred[4][64];
    __shared__ float pooled[64];
    sred[r][o] = partial;
    __syncthreads();
    if (r == 0) {
        float cntf = fmaxf((float)(end - start), 1.0f);
        pooled[o] = (sred[0][o] + sred[1][o] + sred[2][o] + sred[3][o]) / cntf;
    }
    __syncthreads();
    if (t < 10) {
        float acc = bc[t];
#pragma unroll
        for (int k = 0; k < 64; ++k)
            acc = fmaf(pooled[k], wc[k * 10 + t], acc);
        if (f32) ((float*)out)[g * 10 + t] = acc;
        else     ((__hip_bfloat16*)out)[g * 10 + t] = __float2bfloat16(acc);
    }
}

extern "C" void kernel_launch(void* const* d_in, const int* in_sizes, int n_in,
                              void* d_out, int out_size, void* d_ws, size_t ws_size,
                              hipStream_t stream) {
    const int* x          = (const int*)d_in[0];
    const int* edge_index = (const int*)d_in[1];
    const int* batch      = (const int*)d_in[2];

    const int N = in_sizes[2];        // N_NODES
    const int E = in_sizes[1] / 2;    // edge_index is (2, E)
    const int G = out_size / 10;      // num_graphs
    const int NB = (N + 255) / 256;   // scan blocks (<=1024 required)

    // workspace layout
    unsigned short* h = (unsigned short*)d_ws;              // N*64 bf16
    float* agg     = (float*)(h + (size_t)N * 64);          // N*64 f32
    int*   cnt_rep = (int*)(agg + (size_t)N * 64);          // KREP*N (memset 0)
    int*   rowptr  = cnt_rep + (size_t)KREP * N;            // N+1
    int*   tmp     = rowptr + (N + 1);                      // N
    int*   bsum    = tmp + N;                               // NB
    int*   rank    = bsum + NB;                             // E
    int*   csr_src = rank + E;                              // E
    float* wbuf    = (float*)(csr_src + E);

    WParams wp;
    int off = 0;
    for (int i = 0; i < 10; ++i) {
        wp.p[i] = d_in[4 + i];
        wp.off[i] = off;
        off += in_sizes[4 + i];
    }
    wp.off[10] = off;
    const int wtotal = off;

    float* semb_f = wbuf + wp.off[0];
    float* cemb_f = wbuf + wp.off[1];
    float* w1l_f  = wbuf + wp.off[2];
    float* w1r_f  = wbuf + wp.off[3];
    float* b1_f   = wbuf + wp.off[4];
    float* w2l_f  = wbuf + wp.off[5];
    float* w2r_f  = wbuf + wp.off[6];
    float* b2_f   = wbuf + wp.off[7];
    float* wc_f   = wbuf + wp.off[8];
    float* bc_f   = wbuf + wp.off[9];

    const int* src = edge_index;
    const int* tgt = edge_index + E;

    convert_kernel<<<(wtotal + 255) / 256, 256, 0, stream>>>(wp, d_in[4], wbuf, wtotal);
    hipMemsetAsync(cnt_rep, 0, (size_t)KREP * N * sizeof(int), stream);

    embed_kernel<<<(N * 64 + 255) / 256, 256, 0, stream>>>(x, semb_f, cemb_f, h, N);
    count_rank_kernel<<<(E + 255) / 256, 256, 0, stream>>>(tgt, cnt_rep, rank, E, N);

    scan1_kernel<<<NB, 256, 0, stream>>>(cnt_rep, tmp, bsum, N);
    scan2_kernel<<<1, 1024, 0, stream>>>(bsum, NB);
    scan3_kernel<<<NB, 256, 0, stream>>>(tmp, bsum, rowptr, cnt_rep, N);
    fill_kernel<<<(E + 255) / 256, 256, 0, stream>>>(src, tgt, cnt_rep, rank, csr_src, E, N);

    // layer 1
    gather_kernel<<<(N * 64 + 255) / 256, 256, 0, stream>>>(h, rowptr, csr_src, agg, N);
    layer_kernel<<<(N + 63) / 64, 256, 0, stream>>>(h, agg, w1l_f, w1r_f, b1_f, N);

    // layer 2
    gather_kernel<<<(N * 64 + 255) / 256, 256, 0, stream>>>(h, rowptr, csr_src, agg, N);
    layer_kernel<<<(N + 63) / 64, 256, 0, stream>>>(h, agg, w2l_f, w2r_f, b2_f, N);

    // pool + classify
    pool_classify_kernel<<<G, 256, 0, stream>>>(h, batch, wc_f, bc_f, d_out, d_in[4], N);
}

// Round 9
// 363.730 us; speedup vs baseline: 1.5437x; 1.0052x over previous
//
#include <hip/hip_runtime.h>
#include <hip/hip_bf16.h>

// SPRGraphNet: embed -> 2x SAGEConv(mean) -> mean-pool per graph -> linear(64->10)
// Inputs detected fp32 (round 2). CSR + gather aggregation; bf16 h (round 8).
// Round 9: count_rank & fill get 4-edge-per-thread ILP (round 8: one returning
// atomic in flight per wave -> parked at VALUBusy 0.5%; round-2 evidence says
// 4-deep helps ~3x). Replica k = e & 7 (pure function of edge id). Embed fused
// into the count launch (independent work, overlaps atomic latency).

#define KREP 8

struct WParams {
    const void* p[10];
    int off[11];
};

__device__ __forceinline__ float b2f(unsigned short u) {
    return __uint_as_float(((unsigned)u) << 16);
}
__device__ __forceinline__ unsigned short f2b(float f) {
    unsigned x = __float_as_uint(f);
    return (unsigned short)((x + 0x7fff + ((x >> 16) & 1)) >> 16);   // RNE
}
__device__ __forceinline__ float4 b4_to_f4(ushort4 u) {
    return make_float4(b2f(u.x), b2f(u.y), b2f(u.z), b2f(u.w));
}

// Shared inline dtype detection: read first n bf16 of probe; fp32 data
// reinterpreted as bf16 shows |v|>100 or NaN among elements.
__device__ __forceinline__ int detect_f32(const void* probe, int n_bf16) {
    __shared__ int bad;
    if (threadIdx.x == 0) bad = 0;
    __syncthreads();
    const __hip_bfloat16* p = (const __hip_bfloat16*)probe;
    int lbad = 0;
    for (int i = threadIdx.x; i < n_bf16; i += blockDim.x) {
        float v = __bfloat162float(p[i]);
        if (!(fabsf(v) <= 100.0f)) lbad = 1;
    }
    if (lbad) atomicOr(&bad, 1);
    __syncthreads();
    return bad;
}

__device__ __forceinline__ float loadf(const void* p, int i, int f32) {
    return f32 ? ((const float*)p)[i]
               : __bfloat162float(((const __hip_bfloat16*)p)[i]);
}

static __global__ void convert_kernel(WParams wp, const void* probe,
                                      float* __restrict__ dst, int total) {
    int f32 = detect_f32(probe, 1024);
    int gid = blockIdx.x * blockDim.x + threadIdx.x;
    if (gid >= total) return;
    int s = 0;
    while (gid >= wp.off[s + 1]) ++s;
    dst[gid] = loadf(wp.p[s], gid - wp.off[s], f32);
}

// Fused: blocks [0, eb) do 4-edge-ILP count+rank; blocks [eb, ..) do embed.
static __global__ __launch_bounds__(256) void embed_count_kernel(
        const int* __restrict__ x,
        const float* __restrict__ semb, const float* __restrict__ cemb,
        unsigned short* __restrict__ h,
        const int* __restrict__ tgt, int* __restrict__ cnt_rep,
        int* __restrict__ rank,
        int n_nodes, int n_edges, int eb_blocks, int estride) {
    if (blockIdx.x < (unsigned)eb_blocks) {
        int t0 = blockIdx.x * 256 + threadIdx.x;
        int e0 = t0;
        int e1 = t0 + estride;
        int e2 = t0 + 2 * estride;
        int e3 = t0 + 3 * estride;
        // 4 independent tgt loads
        int v0 = (e0 < n_edges) ? tgt[e0] : 0;
        int v1 = (e1 < n_edges) ? tgt[e1] : 0;
        int v2 = (e2 < n_edges) ? tgt[e2] : 0;
        int v3 = (e3 < n_edges) ? tgt[e3] : 0;
        // 4 back-to-back returning atomics (independent; overlap latency)
        int r0 = 0, r1 = 0, r2 = 0, r3 = 0;
        if (e0 < n_edges) r0 = atomicAdd(&cnt_rep[(size_t)(e0 & 7) * n_nodes + v0], 1);
        if (e1 < n_edges) r1 = atomicAdd(&cnt_rep[(size_t)(e1 & 7) * n_nodes + v1], 1);
        if (e2 < n_edges) r2 = atomicAdd(&cnt_rep[(size_t)(e2 & 7) * n_nodes + v2], 1);
        if (e3 < n_edges) r3 = atomicAdd(&cnt_rep[(size_t)(e3 & 7) * n_nodes + v3], 1);
        if (e0 < n_edges) rank[e0] = r0;
        if (e1 < n_edges) rank[e1] = r1;
        if (e2 < n_edges) rank[e2] = r2;
        if (e3 < n_edges) rank[e3] = r3;
    } else {
        int gid = (blockIdx.x - eb_blocks) * 256 + threadIdx.x;
        int node = gid >> 4, c4 = (gid & 15) * 4;
        if (node >= n_nodes) return;
        const float* tab;
        int row, c = c4;
        if (c4 < 32) { tab = semb; row = x[node * 2]; }
        else         { tab = cemb; row = x[node * 2 + 1]; c = c4 - 32; }
        const float* p = tab + (size_t)row * 32 + c;
        ushort4 o;
        o.x = f2b(p[0]); o.y = f2b(p[1]); o.z = f2b(p[2]); o.w = f2b(p[3]);
        *(ushort4*)&h[(size_t)node * 64 + c4] = o;
    }
}

// scan1: node totals from the 8 replicas + block-inclusive scan.
static __global__ __launch_bounds__(256) void scan1_kernel(
        const int* __restrict__ cnt_rep, int* __restrict__ tmp,
        int* __restrict__ bsum, int n) {
    __shared__ int s[256];
    int t = threadIdx.x;
    int i = blockIdx.x * 256 + t;
    int total = 0;
    if (i < n) {
#pragma unroll
        for (int k = 0; k < KREP; ++k) total += cnt_rep[(size_t)k * n + i];
    }
    s[t] = total;
    __syncthreads();
#pragma unroll
    for (int d = 1; d < 256; d <<= 1) {
        int x = (t >= d) ? s[t - d] : 0;
        __syncthreads();
        s[t] += x;
        __syncthreads();
    }
    if (i < n) tmp[i] = s[t];
    if (t == 255) bsum[blockIdx.x] = s[255];
}

static __global__ __launch_bounds__(1024) void scan2_kernel(
        int* __restrict__ bsum, int nb) {     // in-place inclusive scan, nb <= 1024
    __shared__ int s[1024];
    int t = threadIdx.x;
    s[t] = (t < nb) ? bsum[t] : 0;
    __syncthreads();
#pragma unroll
    for (int d = 1; d < 1024; d <<= 1) {
        int x = (t >= d) ? s[t - d] : 0;
        __syncthreads();
        s[t] += x;
        __syncthreads();
    }
    if (t < nb) bsum[t] = s[t];
}

// scan3: write rowptr AND final replica bases (exclusive, rowptr folded in).
static __global__ __launch_bounds__(256) void scan3_kernel(
        const int* __restrict__ tmp, const int* __restrict__ bsum,
        int* __restrict__ rowptr, int* __restrict__ cnt_rep, int n) {
    int i = blockIdx.x * 256 + threadIdx.x;
    if (i >= n) return;
    int bbase = (blockIdx.x > 0) ? bsum[blockIdx.x - 1] : 0;
    int incl = tmp[i] + bbase;                // rowptr[i+1]
    rowptr[i + 1] = incl;
    if (i == 0) rowptr[0] = 0;
    int total = 0;
    int c[KREP];
#pragma unroll
    for (int k = 0; k < KREP; ++k) { c[k] = cnt_rep[(size_t)k * n + i]; total += c[k]; }
    int running = incl - total;
#pragma unroll
    for (int k = 0; k < KREP; ++k) {
        cnt_rep[(size_t)k * n + i] = running;
        running += c[k];
    }
}

// Atomic-free CSR fill, 4 independent chains per thread.
static __global__ __launch_bounds__(256) void fill_kernel(
        const int* __restrict__ src, const int* __restrict__ tgt,
        const int* __restrict__ cnt_rep, const int* __restrict__ rank,
        int* __restrict__ csr_src, int n_edges, int n_nodes, int estride) {
    int t0 = blockIdx.x * 256 + threadIdx.x;
    int e0 = t0;
    int e1 = t0 + estride;
    int e2 = t0 + 2 * estride;
    int e3 = t0 + 3 * estride;
    int v0 = (e0 < n_edges) ? tgt[e0] : 0;
    int v1 = (e1 < n_edges) ? tgt[e1] : 0;
    int v2 = (e2 < n_edges) ? tgt[e2] : 0;
    int v3 = (e3 < n_edges) ? tgt[e3] : 0;
    int r0 = (e0 < n_edges) ? rank[e0] : 0;
    int r1 = (e1 < n_edges) ? rank[e1] : 0;
    int r2 = (e2 < n_edges) ? rank[e2] : 0;
    int r3 = (e3 < n_edges) ? rank[e3] : 0;
    int s0 = (e0 < n_edges) ? src[e0] : 0;
    int s1 = (e1 < n_edges) ? src[e1] : 0;
    int s2 = (e2 < n_edges) ? src[e2] : 0;
    int s3 = (e3 < n_edges) ? src[e3] : 0;
    // 4 independent random reads
    int p0 = (e0 < n_edges) ? cnt_rep[(size_t)(e0 & 7) * n_nodes + v0] : 0;
    int p1 = (e1 < n_edges) ? cnt_rep[(size_t)(e1 & 7) * n_nodes + v1] : 0;
    int p2 = (e2 < n_edges) ? cnt_rep[(size_t)(e2 & 7) * n_nodes + v2] : 0;
    int p3 = (e3 < n_edges) ? cnt_rep[(size_t)(e3 & 7) * n_nodes + v3] : 0;
    if (e0 < n_edges) csr_src[p0 + r0] = s0;
    if (e1 < n_edges) csr_src[p1 + r1] = s1;
    if (e2 < n_edges) csr_src[p2 + r2] = s2;
    if (e3 < n_edges) csr_src[p3 + r3] = s3;
}

// One wave per node. lane = 16*g + j: group g handles edges (i % 4 == g),
// lane loads ushort4 (4 bf16 cols). Cross-group reduce via shfl_xor.
static __global__ __launch_bounds__(256) void gather_kernel(
        const unsigned short* __restrict__ h, const int* __restrict__ rowptr,
        const int* __restrict__ csr_src, float* __restrict__ agg, int n_nodes) {
    int node = (blockIdx.x * 256 + threadIdx.x) >> 6;
    int lane = threadIdx.x & 63;
    if (node >= n_nodes) return;
    int g = lane >> 4, j = lane & 15;
    int beg = rowptr[node], end = rowptr[node + 1];

    float4 acc = make_float4(0.f, 0.f, 0.f, 0.f);
    int i = beg + g;
    for (; i + 12 < end; i += 16) {
        int s0 = csr_src[i];
        int s1 = csr_src[i + 4];
        int s2 = csr_src[i + 8];
        int s3 = csr_src[i + 12];
        float4 v0 = b4_to_f4(*reinterpret_cast<const ushort4*>(h + (size_t)s0 * 64 + j * 4));
        float4 v1 = b4_to_f4(*reinterpret_cast<const ushort4*>(h + (size_t)s1 * 64 + j * 4));
        float4 v2 = b4_to_f4(*reinterpret_cast<const ushort4*>(h + (size_t)s2 * 64 + j * 4));
        float4 v3 = b4_to_f4(*reinterpret_cast<const ushort4*>(h + (size_t)s3 * 64 + j * 4));
        acc.x += v0.x + v1.x + v2.x + v3.x;
        acc.y += v0.y + v1.y + v2.y + v3.y;
        acc.z += v0.z + v1.z + v2.z + v3.z;
        acc.w += v0.w + v1.w + v2.w + v3.w;
    }
    for (; i + 4 < end; i += 8) {
        int s0 = csr_src[i];
        int s1 = csr_src[i + 4];
        float4 v0 = b4_to_f4(*reinterpret_cast<const ushort4*>(h + (size_t)s0 * 64 + j * 4));
        float4 v1 = b4_to_f4(*reinterpret_cast<const ushort4*>(h + (size_t)s1 * 64 + j * 4));
        acc.x += v0.x + v1.x;
        acc.y += v0.y + v1.y;
        acc.z += v0.z + v1.z;
        acc.w += v0.w + v1.w;
    }
    if (i < end) {
        int s = csr_src[i];
        float4 v = b4_to_f4(*reinterpret_cast<const ushort4*>(h + (size_t)s * 64 + j * 4));
        acc.x += v.x; acc.y += v.y; acc.z += v.z; acc.w += v.w;
    }
#pragma unroll
    for (int m = 16; m < 64; m <<= 1) {
        acc.x += __shfl_xor(acc.x, m, 64);
        acc.y += __shfl_xor(acc.y, m, 64);
        acc.z += __shfl_xor(acc.z, m, 64);
        acc.w += __shfl_xor(acc.w, m, 64);
    }
    if (g == 0) {
        float inv = 1.0f / fmaxf((float)(end - beg), 1.0f);
        acc.x *= inv; acc.y *= inv; acc.z *= inv; acc.w *= inv;
        *reinterpret_cast<float4*>(agg + (size_t)node * 64 + j * 4) = acc;
    }
}

// h = relu([agg | h] @ [wl; wr] + b), in place (bf16 h, fp32 agg/compute).
// Block: 256 threads = 16x16; tile = 64 nodes x 64 cols; 4x4 register tiling.
static __global__ __launch_bounds__(256) void layer_kernel(
        unsigned short* __restrict__ h, const float* __restrict__ agg,
        const float* __restrict__ wl, const float* __restrict__ wr,
        const float* __restrict__ b, int n_nodes) {
    __shared__ float inS[64][132];   // [node][k], +4 pad
    __shared__ float wS[128][64];    // [k][col], rows 0..63 = wl, 64..127 = wr
    int t = threadIdx.x;
    int base = blockIdx.x * 64;

    const float4* wl4 = (const float4*)wl;
    const float4* wr4 = (const float4*)wr;
#pragma unroll
    for (int r = 0; r < 4; ++r) {
        int i = t + 256 * r;
        int k = i >> 4, c = (i & 15) * 4;
        *(float4*)&wS[k][c] = wl4[i];
        *(float4*)&wS[64 + k][c] = wr4[i];
    }
#pragma unroll
    for (int r = 0; r < 4; ++r) {
        int i = t + 256 * r;
        int n = i >> 4, c = (i & 15) * 4;
        int node = base + n;
        float4 va = make_float4(0.f, 0.f, 0.f, 0.f);
        float4 vh = make_float4(0.f, 0.f, 0.f, 0.f);
        if (node < n_nodes) {
            va = *(const float4*)&agg[(size_t)node * 64 + c];
            vh = b4_to_f4(*(const ushort4*)&h[(size_t)node * 64 + c]);
        }
        *(float4*)&inS[n][c] = va;
        *(float4*)&inS[n][64 + c] = vh;
    }
    __syncthreads();

    int tx = t & 15, ty = t >> 4;
    int c0 = tx * 4, n0 = ty * 4;
    float4 bias = *(const float4*)&b[c0];
    float acc[4][4];
#pragma unroll
    for (int i = 0; i < 4; ++i) {
        acc[i][0] = bias.x; acc[i][1] = bias.y;
        acc[i][2] = bias.z; acc[i][3] = bias.w;
    }

#pragma unroll 4
    for (int k = 0; k < 128; k += 4) {
        float4 a0 = *(const float4*)&inS[n0 + 0][k];
        float4 a1 = *(const float4*)&inS[n0 + 1][k];
        float4 a2 = *(const float4*)&inS[n0 + 2][k];
        float4 a3 = *(const float4*)&inS[n0 + 3][k];
        float4 w0 = *(const float4*)&wS[k + 0][c0];
        float4 w1 = *(const float4*)&wS[k + 1][c0];
        float4 w2 = *(const float4*)&wS[k + 2][c0];
        float4 w3 = *(const float4*)&wS[k + 3][c0];
#define ROW(i, ai)                                                        \
        acc[i][0] = fmaf(ai.x, w0.x, fmaf(ai.y, w1.x, fmaf(ai.z, w2.x,    \
                    fmaf(ai.w, w3.x, acc[i][0]))));                       \
        acc[i][1] = fmaf(ai.x, w0.y, fmaf(ai.y, w1.y, fmaf(ai.z, w2.y,    \
                    fmaf(ai.w, w3.y, acc[i][1]))));                       \
        acc[i][2] = fmaf(ai.x, w0.z, fmaf(ai.y, w1.z, fmaf(ai.z, w2.z,    \
                    fmaf(ai.w, w3.z, acc[i][2]))));                       \
        acc[i][3] = fmaf(ai.x, w0.w, fmaf(ai.y, w1.w, fmaf(ai.z, w2.w,    \
                    fmaf(ai.w, w3.w, acc[i][3]))));
        ROW(0, a0) ROW(1, a1) ROW(2, a2) ROW(3, a3)
#undef ROW
    }

#pragma unroll
    for (int i = 0; i < 4; ++i) {
        int node = base + n0 + i;
        if (node < n_nodes) {
            ushort4 o;
            o.x = f2b(fmaxf(acc[i][0], 0.f));
            o.y = f2b(fmaxf(acc[i][1], 0.f));
            o.z = f2b(fmaxf(acc[i][2], 0.f));
            o.w = f2b(fmaxf(acc[i][3], 0.f));
            *(ushort4*)&h[(size_t)node * 64 + c0] = o;
        }
    }
}

// batch is sorted: binary-search [start,end) per graph; mean-pool then classify.
static __global__ __launch_bounds__(256) void pool_classify_kernel(
        const unsigned short* __restrict__ h, const int* __restrict__ batch,
        const float* __restrict__ wc, const float* __restrict__ bc,
        void* __restrict__ out, const void* probe, int n_nodes) {
    int f32 = detect_f32(probe, 1024);
    int g = blockIdx.x;
    int t = threadIdx.x;
    int lo = 0, hi = n_nodes;
    while (lo < hi) { int mid = (lo + hi) >> 1; if (batch[mid] < g) lo = mid + 1; else hi = mid; }
    int start = lo;
    hi = n_nodes;
    while (lo < hi) { int mid = (lo + hi) >> 1; if (batch[mid] < g + 1) lo = mid + 1; else hi = mid; }
    int end = lo;

    int r = t >> 6, o = t & 63;
    float partial = 0.0f;
    for (int n = start + r; n < end; n += 4) partial += b2f(h[(size_t)n * 64 + o]);
    __shared__ float sred[4][64];
    __shared__ float pooled[64];
    sred[r][o] = partial;
    __syncthreads();
    if (r == 0) {
        float cntf = fmaxf((float)(end - start), 1.0f);
        pooled[o] = (sred[0][o] + sred[1][o] + sred[2][o] + sred[3][o]) / cntf;
    }
    __syncthreads();
    if (t < 10) {
        float acc = bc[t];
#pragma unroll
        for (int k = 0; k < 64; ++k)
            acc = fmaf(pooled[k], wc[k * 10 + t], acc);
        if (f32) ((float*)out)[g * 10 + t] = acc;
        else     ((__hip_bfloat16*)out)[g * 10 + t] = __float2bfloat16(acc);
    }
}

extern "C" void kernel_launch(void* const* d_in, const int* in_sizes, int n_in,
                              void* d_out, int out_size, void* d_ws, size_t ws_size,
                              hipStream_t stream) {
    const int* x          = (const int*)d_in[0];
    const int* edge_index = (const int*)d_in[1];
    const int* batch      = (const int*)d_in[2];

    const int N = in_sizes[2];        // N_NODES
    const int E = in_sizes[1] / 2;    // edge_index is (2, E)
    const int G = out_size / 10;      // num_graphs
    const int NB = (N + 255) / 256;   // scan blocks (<=1024 required)

    // 4 edges per thread
    const int EB = (E + 1023) / 1024;         // edge blocks
    const int ESTRIDE = EB * 256;
    const int MB = (N * 16 + 255) / 256;      // embed blocks (ushort4 per thread)

    // workspace layout
    unsigned short* h = (unsigned short*)d_ws;              // N*64 bf16
    float* agg     = (float*)(h + (size_t)N * 64);          // N*64 f32
    int*   cnt_rep = (int*)(agg + (size_t)N * 64);          // KREP*N (memset 0)
    int*   rowptr  = cnt_rep + (size_t)KREP * N;            // N+1
    int*   tmp     = rowptr + (N + 1);                      // N
    int*   bsum    = tmp + N;                               // NB
    int*   rank    = bsum + NB;                             // E
    int*   csr_src = rank + E;                              // E
    float* wbuf    = (float*)(csr_src + E);

    WParams wp;
    int off = 0;
    for (int i = 0; i < 10; ++i) {
        wp.p[i] = d_in[4 + i];
        wp.off[i] = off;
        off += in_sizes[4 + i];
    }
    wp.off[10] = off;
    const int wtotal = off;

    float* semb_f = wbuf + wp.off[0];
    float* cemb_f = wbuf + wp.off[1];
    float* w1l_f  = wbuf + wp.off[2];
    float* w1r_f  = wbuf + wp.off[3];
    float* b1_f   = wbuf + wp.off[4];
    float* w2l_f  = wbuf + wp.off[5];
    float* w2r_f  = wbuf + wp.off[6];
    float* b2_f   = wbuf + wp.off[7];
    float* wc_f   = wbuf + wp.off[8];
    float* bc_f   = wbuf + wp.off[9];

    const int* src = edge_index;
    const int* tgt = edge_index + E;

    convert_kernel<<<(wtotal + 255) / 256, 256, 0, stream>>>(wp, d_in[4], wbuf, wtotal);
    hipMemsetAsync(cnt_rep, 0, (size_t)KREP * N * sizeof(int), stream);

    embed_count_kernel<<<EB + MB, 256, 0, stream>>>(x, semb_f, cemb_f, h,
                                                    tgt, cnt_rep, rank,
                                                    N, E, EB, ESTRIDE);

    scan1_kernel<<<NB, 256, 0, stream>>>(cnt_rep, tmp, bsum, N);
    scan2_kernel<<<1, 1024, 0, stream>>>(bsum, NB);
    scan3_kernel<<<NB, 256, 0, stream>>>(tmp, bsum, rowptr, cnt_rep, N);
    fill_kernel<<<EB, 256, 0, stream>>>(src, tgt, cnt_rep, rank, csr_src, E, N, ESTRIDE);

    // layer 1
    gather_kernel<<<(N * 64 + 255) / 256, 256, 0, stream>>>(h, rowptr, csr_src, agg, N);
    layer_kernel<<<(N + 63) / 64, 256, 0, stream>>>(h, agg, w1l_f, w1r_f, b1_f, N);

    // layer 2
    gather_kernel<<<(N * 64 + 255) / 256, 256, 0, stream>>>(h, rowptr, csr_src, agg, N);
    layer_kernel<<<(N + 63) / 64, 256, 0, stream>>>(h, agg, w2l_f, w2r_f, b2_f, N);

    // pool + classify
    pool_classify_kernel<<<G, 256, 0, stream>>>(h, batch, wc_f, bc_f, d_out, d_in[4], N);
}

// Round 10
// 306.472 us; speedup vs baseline: 1.8321x; 1.1868x over previous
//
#include <hip/hip_runtime.h>
#include <hip/hip_bf16.h>

// SPRGraphNet: embed -> 2x SAGEConv(mean) -> mean-pool per graph -> linear(64->10)
// Inputs detected fp32 (round 2). bf16 h (round 8).
// Round 10: CSR built by two-phase counting sort (bucket = tgt&511, then
// node within bucket) using only LDS atomics. Rounds 7/9 proved returning
// global atomics are a hard ~23.5 G/s device rate (KREP and ILP both no-ops);
// this build has ZERO global returning atomics.

struct WParams {
    const void* p[10];
    int off[11];
};

__device__ __forceinline__ float b2f(unsigned short u) {
    return __uint_as_float(((unsigned)u) << 16);
}
__device__ __forceinline__ unsigned short f2b(float f) {
    unsigned x = __float_as_uint(f);
    return (unsigned short)((x + 0x7fff + ((x >> 16) & 1)) >> 16);   // RNE
}
__device__ __forceinline__ float4 b4_to_f4(ushort4 u) {
    return make_float4(b2f(u.x), b2f(u.y), b2f(u.z), b2f(u.w));
}

// Inline dtype detection: fp32 data read as bf16 shows |v|>100 / NaN.
__device__ __forceinline__ int detect_f32(const void* probe, int n_bf16) {
    __shared__ int bad;
    if (threadIdx.x == 0) bad = 0;
    __syncthreads();
    const __hip_bfloat16* p = (const __hip_bfloat16*)probe;
    int lbad = 0;
    for (int i = threadIdx.x; i < n_bf16; i += blockDim.x) {
        float v = __bfloat162float(p[i]);
        if (!(fabsf(v) <= 100.0f)) lbad = 1;
    }
    if (lbad) atomicOr(&bad, 1);
    __syncthreads();
    return bad;
}

__device__ __forceinline__ float loadf(const void* p, int i, int f32) {
    return f32 ? ((const float*)p)[i]
               : __bfloat162float(((const __hip_bfloat16*)p)[i]);
}

static __global__ void convert_kernel(WParams wp, const void* probe,
                                      float* __restrict__ dst, int total) {
    int f32 = detect_f32(probe, 1024);
    int gid = blockIdx.x * blockDim.x + threadIdx.x;
    if (gid >= total) return;
    int s = 0;
    while (gid >= wp.off[s + 1]) ++s;
    dst[gid] = loadf(wp.p[s], gid - wp.off[s], f32);
}

// Blocks [0,NBE): LDS histogram of tgt&511 over a 4096-edge tile -> H[bin][blk].
// Blocks [NBE,..): embed (ushort4 per thread).
static __global__ __launch_bounds__(256) void hist1_embed_kernel(
        const int* __restrict__ tgt, int* __restrict__ H, int NBE,
        const int* __restrict__ x,
        const float* __restrict__ semb, const float* __restrict__ cemb,
        unsigned short* __restrict__ h, int n_nodes, int n_edges) {
    if (blockIdx.x < (unsigned)NBE) {
        __shared__ int lh[512];
        int t = threadIdx.x;
        lh[t] = 0; lh[t + 256] = 0;
        __syncthreads();
        int base = blockIdx.x * 4096;
        for (int i = t; i < 4096; i += 256) {
            int e = base + i;
            if (e < n_edges) atomicAdd(&lh[tgt[e] & 511], 1);
        }
        __syncthreads();
        H[(size_t)t * NBE + blockIdx.x] = lh[t];
        H[(size_t)(t + 256) * NBE + blockIdx.x] = lh[t + 256];
    } else {
        int gid = (blockIdx.x - NBE) * 256 + threadIdx.x;
        int node = gid >> 4, c4 = (gid & 15) * 4;
        if (node >= n_nodes) return;
        const float* tab;
        int row, c = c4;
        if (c4 < 32) { tab = semb; row = x[node * 2]; }
        else         { tab = cemb; row = x[node * 2 + 1]; c = c4 - 32; }
        const float* p = tab + (size_t)row * 32 + c;
        ushort4 o;
        o.x = f2b(p[0]); o.y = f2b(p[1]); o.z = f2b(p[2]); o.w = f2b(p[3]);
        *(ushort4*)&h[(size_t)node * 64 + c4] = o;
    }
}

// scanA: 512 elements per block (2/thread), block-inclusive -> tmp, sums -> bsum.
static __global__ __launch_bounds__(256) void scanA_kernel(
        const int* __restrict__ in, int* __restrict__ tmp,
        int* __restrict__ bsum, int n) {
    __shared__ int s[256];
    int t = threadIdx.x;
    int i0 = blockIdx.x * 512 + 2 * t;
    int a0 = (i0 < n) ? in[i0] : 0;
    int a1 = (i0 + 1 < n) ? in[i0 + 1] : 0;
    s[t] = a0 + a1;
    __syncthreads();
#pragma unroll
    for (int d = 1; d < 256; d <<= 1) {
        int x = (t >= d) ? s[t - d] : 0;
        __syncthreads();
        s[t] += x;
        __syncthreads();
    }
    if (i0 < n) tmp[i0] = s[t] - a1;          // inclusive at i0
    if (i0 + 1 < n) tmp[i0 + 1] = s[t];       // inclusive at i0+1
    if (t == 255) bsum[blockIdx.x] = s[255];
}

static __global__ __launch_bounds__(1024) void scan2_kernel(
        int* __restrict__ bsum, int nb) {     // in-place inclusive scan, nb <= 1024
    __shared__ int s[1024];
    int t = threadIdx.x;
    s[t] = (t < nb) ? bsum[t] : 0;
    __syncthreads();
#pragma unroll
    for (int d = 1; d < 1024; d <<= 1) {
        int x = (t >= d) ? s[t - d] : 0;
        __syncthreads();
        s[t] += x;
        __syncthreads();
    }
    if (t < nb) bsum[t] = s[t];
}

// scanC: B[i] = global exclusive prefix of H at i.
static __global__ __launch_bounds__(256) void scanC_kernel(
        const int* __restrict__ tmp, const int* __restrict__ bsum,
        const int* __restrict__ H, int* __restrict__ B, int n) {
    int i = blockIdx.x * 256 + threadIdx.x;
    if (i >= n) return;
    int blk = i / 512;
    int basep = (blk > 0) ? bsum[blk - 1] : 0;
    B[i] = tmp[i] + basep - H[i];
}

// scatter1: re-read tile; LDS cursors seeded from B give global slots directly.
// Write packed (src,tgt) records grouped by bucket.
static __global__ __launch_bounds__(256) void scatter1_kernel(
        const int* __restrict__ src, const int* __restrict__ tgt,
        const int* __restrict__ B, unsigned long long* __restrict__ rec,
        int NBE, int n_edges) {
    __shared__ int cur[512];
    int t = threadIdx.x;
    cur[t]       = B[(size_t)t * NBE + blockIdx.x];
    cur[t + 256] = B[(size_t)(t + 256) * NBE + blockIdx.x];
    __syncthreads();
    int base = blockIdx.x * 4096;
    for (int i = t; i < 4096; i += 256) {
        int e = base + i;
        if (e < n_edges) {
            int tg = tgt[e];
            int pos = atomicAdd(&cur[tg & 511], 1);
            rec[pos] = ((unsigned long long)(unsigned)src[e] << 32) | (unsigned)tg;
        }
    }
}

// csr2: one block per bucket b. Records [B[b*NBE], next) share tgt&511==b;
// node = b + (q<<9), q = tgt>>9 (<196). LDS hist+scan -> start/cnt + scatter.
static __global__ __launch_bounds__(256) void csr2_kernel(
        const unsigned long long* __restrict__ rec, const int* __restrict__ B,
        int NBE, int* __restrict__ csr_src,
        int* __restrict__ startA, int* __restrict__ cntA,
        int n_nodes, int n_edges) {
    __shared__ int hist[256], scn[256], cursor[256];
    __shared__ int sbeg, send;
    int b = blockIdx.x;
    int t = threadIdx.x;
    hist[t] = 0;
    if (t == 0) {
        sbeg = B[(size_t)b * NBE];
        send = (b == 511) ? n_edges : B[(size_t)(b + 1) * NBE];
    }
    __syncthreads();
    int beg = sbeg, end = send;
    for (int i = beg + t; i < end; i += 256) {
        int tg = (int)(unsigned)rec[i];
        atomicAdd(&hist[tg >> 9], 1);
    }
    __syncthreads();
    scn[t] = hist[t];
    __syncthreads();
#pragma unroll
    for (int d = 1; d < 256; d <<= 1) {
        int x = (t >= d) ? scn[t - d] : 0;
        __syncthreads();
        scn[t] += x;
        __syncthreads();
    }
    int excl = scn[t] - hist[t];
    cursor[t] = beg + excl;
    int n = b + (t << 9);
    if (n < n_nodes) { startA[n] = beg + excl; cntA[n] = hist[t]; }
    __syncthreads();
    for (int i = beg + t; i < end; i += 256) {
        unsigned long long r = rec[i];
        int tg = (int)(unsigned)r;
        int sc = (int)(unsigned)(r >> 32);
        int p = atomicAdd(&cursor[tg >> 9], 1);
        csr_src[p] = sc;
    }
}

// One wave per node. lane = 16*g + j: group g handles edges (i % 4 == g),
// lane loads ushort4 (4 bf16 cols). Cross-group reduce via shfl_xor.
static __global__ __launch_bounds__(256) void gather_kernel(
        const unsigned short* __restrict__ h, const int* __restrict__ startA,
        const int* __restrict__ cntA,
        const int* __restrict__ csr_src, float* __restrict__ agg, int n_nodes) {
    int node = (blockIdx.x * 256 + threadIdx.x) >> 6;
    int lane = threadIdx.x & 63;
    if (node >= n_nodes) return;
    int g = lane >> 4, j = lane & 15;
    int beg = startA[node], deg = cntA[node];
    int end = beg + deg;

    float4 acc = make_float4(0.f, 0.f, 0.f, 0.f);
    int i = beg + g;
    for (; i + 12 < end; i += 16) {
        int s0 = csr_src[i];
        int s1 = csr_src[i + 4];
        int s2 = csr_src[i + 8];
        int s3 = csr_src[i + 12];
        float4 v0 = b4_to_f4(*reinterpret_cast<const ushort4*>(h + (size_t)s0 * 64 + j * 4));
        float4 v1 = b4_to_f4(*reinterpret_cast<const ushort4*>(h + (size_t)s1 * 64 + j * 4));
        float4 v2 = b4_to_f4(*reinterpret_cast<const ushort4*>(h + (size_t)s2 * 64 + j * 4));
        float4 v3 = b4_to_f4(*reinterpret_cast<const ushort4*>(h + (size_t)s3 * 64 + j * 4));
        acc.x += v0.x + v1.x + v2.x + v3.x;
        acc.y += v0.y + v1.y + v2.y + v3.y;
        acc.z += v0.z + v1.z + v2.z + v3.z;
        acc.w += v0.w + v1.w + v2.w + v3.w;
    }
    for (; i + 4 < end; i += 8) {
        int s0 = csr_src[i];
        int s1 = csr_src[i + 4];
        float4 v0 = b4_to_f4(*reinterpret_cast<const ushort4*>(h + (size_t)s0 * 64 + j * 4));
        float4 v1 = b4_to_f4(*reinterpret_cast<const ushort4*>(h + (size_t)s1 * 64 + j * 4));
        acc.x += v0.x + v1.x;
        acc.y += v0.y + v1.y;
        acc.z += v0.z + v1.z;
        acc.w += v0.w + v1.w;
    }
    if (i < end) {
        int s = csr_src[i];
        float4 v = b4_to_f4(*reinterpret_cast<const ushort4*>(h + (size_t)s * 64 + j * 4));
        acc.x += v.x; acc.y += v.y; acc.z += v.z; acc.w += v.w;
    }
#pragma unroll
    for (int m = 16; m < 64; m <<= 1) {
        acc.x += __shfl_xor(acc.x, m, 64);
        acc.y += __shfl_xor(acc.y, m, 64);
        acc.z += __shfl_xor(acc.z, m, 64);
        acc.w += __shfl_xor(acc.w, m, 64);
    }
    if (g == 0) {
        float inv = 1.0f / fmaxf((float)deg, 1.0f);
        acc.x *= inv; acc.y *= inv; acc.z *= inv; acc.w *= inv;
        *reinterpret_cast<float4*>(agg + (size_t)node * 64 + j * 4) = acc;
    }
}

// h = relu([agg | h] @ [wl; wr] + b), in place (bf16 h, fp32 agg/compute).
static __global__ __launch_bounds__(256) void layer_kernel(
        unsigned short* __restrict__ h, const float* __restrict__ agg,
        const float* __restrict__ wl, const float* __restrict__ wr,
        const float* __restrict__ b, int n_nodes) {
    __shared__ float inS[64][132];   // [node][k], +4 pad
    __shared__ float wS[128][64];    // [k][col], rows 0..63 = wl, 64..127 = wr
    int t = threadIdx.x;
    int base = blockIdx.x * 64;

    const float4* wl4 = (const float4*)wl;
    const float4* wr4 = (const float4*)wr;
#pragma unroll
    for (int r = 0; r < 4; ++r) {
        int i = t + 256 * r;
        int k = i >> 4, c = (i & 15) * 4;
        *(float4*)&wS[k][c] = wl4[i];
        *(float4*)&wS[64 + k][c] = wr4[i];
    }
#pragma unroll
    for (int r = 0; r < 4; ++r) {
        int i = t + 256 * r;
        int n = i >> 4, c = (i & 15) * 4;
        int node = base + n;
        float4 va = make_float4(0.f, 0.f, 0.f, 0.f);
        float4 vh = make_float4(0.f, 0.f, 0.f, 0.f);
        if (node < n_nodes) {
            va = *(const float4*)&agg[(size_t)node * 64 + c];
            vh = b4_to_f4(*(const ushort4*)&h[(size_t)node * 64 + c]);
        }
        *(float4*)&inS[n][c] = va;
        *(float4*)&inS[n][64 + c] = vh;
    }
    __syncthreads();

    int tx = t & 15, ty = t >> 4;
    int c0 = tx * 4, n0 = ty * 4;
    float4 bias = *(const float4*)&b[c0];
    float acc[4][4];
#pragma unroll
    for (int i = 0; i < 4; ++i) {
        acc[i][0] = bias.x; acc[i][1] = bias.y;
        acc[i][2] = bias.z; acc[i][3] = bias.w;
    }

#pragma unroll 4
    for (int k = 0; k < 128; k += 4) {
        float4 a0 = *(const float4*)&inS[n0 + 0][k];
        float4 a1 = *(const float4*)&inS[n0 + 1][k];
        float4 a2 = *(const float4*)&inS[n0 + 2][k];
        float4 a3 = *(const float4*)&inS[n0 + 3][k];
        float4 w0 = *(const float4*)&wS[k + 0][c0];
        float4 w1 = *(const float4*)&wS[k + 1][c0];
        float4 w2 = *(const float4*)&wS[k + 2][c0];
        float4 w3 = *(const float4*)&wS[k + 3][c0];
#define ROW(i, ai)                                                        \
        acc[i][0] = fmaf(ai.x, w0.x, fmaf(ai.y, w1.x, fmaf(ai.z, w2.x,    \
                    fmaf(ai.w, w3.x, acc[i][0]))));                       \
        acc[i][1] = fmaf(ai.x, w0.y, fmaf(ai.y, w1.y, fmaf(ai.z, w2.y,    \
                    fmaf(ai.w, w3.y, acc[i][1]))));                       \
        acc[i][2] = fmaf(ai.x, w0.z, fmaf(ai.y, w1.z, fmaf(ai.z, w2.z,    \
                    fmaf(ai.w, w3.z, acc[i][2]))));                       \
        acc[i][3] = fmaf(ai.x, w0.w, fmaf(ai.y, w1.w, fmaf(ai.z, w2.w,    \
                    fmaf(ai.w, w3.w, acc[i][3]))));
        ROW(0, a0) ROW(1, a1) ROW(2, a2) ROW(3, a3)
#undef ROW
    }

#pragma unroll
    for (int i = 0; i < 4; ++i) {
        int node = base + n0 + i;
        if (node < n_nodes) {
            ushort4 o;
            o.x = f2b(fmaxf(acc[i][0], 0.f));
            o.y = f2b(fmaxf(acc[i][1], 0.f));
            o.z = f2b(fmaxf(acc[i][2], 0.f));
            o.w = f2b(fmaxf(acc[i][3], 0.f));
            *(ushort4*)&h[(size_t)node * 64 + c0] = o;
        }
    }
}

// batch is sorted: binary-search [start,end) per graph; mean-pool then classify.
static __global__ __launch_bounds__(256) void pool_classify_kernel(
        const unsigned short* __restrict__ h, const int* __restrict__ batch,
        const float* __restrict__ wc, const float* __restrict__ bc,
        void* __restrict__ out, const void* probe, int n_nodes) {
    int f32 = detect_f32(probe, 1024);
    int g = blockIdx.x;
    int t = threadIdx.x;
    int lo = 0, hi = n_nodes;
    while (lo < hi) { int mid = (lo + hi) >> 1; if (batch[mid] < g) lo = mid + 1; else hi = mid; }
    int start = lo;
    hi = n_nodes;
    while (lo < hi) { int mid = (lo + hi) >> 1; if (batch[mid] < g + 1) lo = mid + 1; else hi = mid; }
    int end = lo;

    int r = t >> 6, o = t & 63;
    float partial = 0.0f;
    for (int n = start + r; n < end; n += 4) partial += b2f(h[(size_t)n * 64 + o]);
    __shared__ float sred[4][64];
    __shared__ float pooled[64];
    sred[r][o] = partial;
    __syncthreads();
    if (r == 0) {
        float cntf = fmaxf((float)(end - start), 1.0f);
        pooled[o] = (sred[0][o] + sred[1][o] + sred[2][o] + sred[3][o]) / cntf;
    }
    __syncthreads();
    if (t < 10) {
        float acc = bc[t];
#pragma unroll
        for (int k = 0; k < 64; ++k)
            acc = fmaf(pooled[k], wc[k * 10 + t], acc);
        if (f32) ((float*)out)[g * 10 + t] = acc;
        else     ((__hip_bfloat16*)out)[g * 10 + t] = __float2bfloat16(acc);
    }
}

extern "C" void kernel_launch(void* const* d_in, const int* in_sizes, int n_in,
                              void* d_out, int out_size, void* d_ws, size_t ws_size,
                              hipStream_t stream) {
    const int* x          = (const int*)d_in[0];
    const int* edge_index = (const int*)d_in[1];
    const int* batch      = (const int*)d_in[2];

    const int N = in_sizes[2];        // N_NODES
    const int E = in_sizes[1] / 2;    // edge_index is (2, E)
    const int G = out_size / 10;      // num_graphs

    const int NBE = (E + 4095) / 4096;          // edge tiles
    const int Hsz = 512 * NBE;                  // histogram matrix size
    const int SB  = (Hsz + 511) / 512;          // scanA blocks (<=1024)
    const int MB  = (N * 16 + 255) / 256;       // embed blocks

    // workspace layout (rec needs 8B alignment: h is N*128 bytes, mult of 8)
    unsigned short* h = (unsigned short*)d_ws;              // N*64 bf16
    unsigned long long* rec = (unsigned long long*)(h + (size_t)N * 64); // E
    float* agg     = (float*)(rec + E);                     // N*64 f32
    int*   startA  = (int*)(agg + (size_t)N * 64);          // N
    int*   cntA    = startA + N;                            // N
    int*   H       = cntA + N;                              // Hsz
    int*   B       = H + Hsz;                               // Hsz
    int*   tmpS    = B + Hsz;                               // Hsz
    int*   bsumS   = tmpS + Hsz;                            // SB (<=1024)
    int*   csr_src = bsumS + 1024;                          // E
    float* wbuf    = (float*)(csr_src + E);

    WParams wp;
    int off = 0;
    for (int i = 0; i < 10; ++i) {
        wp.p[i] = d_in[4 + i];
        wp.off[i] = off;
        off += in_sizes[4 + i];
    }
    wp.off[10] = off;
    const int wtotal = off;

    float* semb_f = wbuf + wp.off[0];
    float* cemb_f = wbuf + wp.off[1];
    float* w1l_f  = wbuf + wp.off[2];
    float* w1r_f  = wbuf + wp.off[3];
    float* b1_f   = wbuf + wp.off[4];
    float* w2l_f  = wbuf + wp.off[5];
    float* w2r_f  = wbuf + wp.off[6];
    float* b2_f   = wbuf + wp.off[7];
    float* wc_f   = wbuf + wp.off[8];
    float* bc_f   = wbuf + wp.off[9];

    const int* src = edge_index;
    const int* tgt = edge_index + E;

    convert_kernel<<<(wtotal + 255) / 256, 256, 0, stream>>>(wp, d_in[4], wbuf, wtotal);

    // CSR build by counting sort (no global returning atomics, no memset)
    hist1_embed_kernel<<<NBE + MB, 256, 0, stream>>>(tgt, H, NBE, x, semb_f,
                                                     cemb_f, h, N, E);
    scanA_kernel<<<SB, 256, 0, stream>>>(H, tmpS, bsumS, Hsz);
    scan2_kernel<<<1, 1024, 0, stream>>>(bsumS, SB);
    scanC_kernel<<<(Hsz + 255) / 256, 256, 0, stream>>>(tmpS, bsumS, H, B, Hsz);
    scatter1_kernel<<<NBE, 256, 0, stream>>>(src, tgt, B, rec, NBE, E);
    csr2_kernel<<<512, 256, 0, stream>>>(rec, B, NBE, csr_src, startA, cntA, N, E);

    // layer 1
    gather_kernel<<<(N * 64 + 255) / 256, 256, 0, stream>>>(h, startA, cntA, csr_src, agg, N);
    layer_kernel<<<(N + 63) / 64, 256, 0, stream>>>(h, agg, w1l_f, w1r_f, b1_f, N);

    // layer 2
    gather_kernel<<<(N * 64 + 255) / 256, 256, 0, stream>>>(h, startA, cntA, csr_src, agg, N);
    layer_kernel<<<(N + 63) / 64, 256, 0, stream>>>(h, agg, w2l_f, w2r_f, b2_f, N);

    // pool + classify
    pool_classify_kernel<<<G, 256, 0, stream>>>(h, batch, wc_f, bc_f, d_out, d_in[4], N);
}